// Round 12
// baseline (181.148 us; speedup 1.0000x reference)
//
#include <hip/hip_runtime.h>
#include <hip/hip_fp16.h>
#include <math.h>
#include <stdint.h>

#define N_NODES 100000
#define N_EDGES 1600000
#define NEG_SLOPE 0.2f
#define LOG2E 1.44269504088896340736f

#define CB     128                            // dst nodes per bucket
#define CBBITS 7
#define NCB    ((N_NODES + CB - 1) / CB)      // 782 buckets
#define TP     2048                           // edges per partition block
#define NPB    ((N_EDGES + TP - 1) / TP)      // 782 partition blocks
#define WINB   2560                           // per-bucket record window (mean 2174, +11 sigma)
#define NB_NODE1 ((N_NODES * 8 + 511) / 512)  // node1 blocks in fused kernel
#define N8     ((size_t)N_NODES * 8)

typedef int nt_int4 __attribute__((ext_vector_type(4)));

// ---------------- fused: partition-route + node transform ---------------
// Blocks [0, NPB): edge routing. LDS rank-sort by bucket (1 LDS atomic +
// scan + direct stage write), then each thread appends its 2 bins' runs
// to the buckets' GLOBAL windows: one device atomicAdd per nonempty
// (block,bucket) run (~725/block) + ~2.8 record stores. k_csr then reads
// each bucket's records as ONE dense segment — no scattered slice fetch.
// Blocks [NPB, ...): node transform (logits pre-scaled log2e).
__global__ void __launch_bounds__(512) k_np(
        const int* __restrict__ src, const int* __restrict__ dst,
        int* __restrict__ gcur, unsigned* __restrict__ pairs,
        const float* __restrict__ x, const float* __restrict__ W1,
        const float* __restrict__ a_src1, const float* __restrict__ a_dst1,
        __half* __restrict__ xh, __half* __restrict__ as1h,
        float* __restrict__ ad1) {
    __shared__ int lcnt[1024];           // bins (782 used): counts -> bases
    __shared__ unsigned stage[TP];       // 8 KB
    __shared__ int wred[8];
    int t = threadIdx.x;

    if (blockIdx.x >= NPB) {
        // ---------- node1 half ----------
        int gid  = (blockIdx.x - NPB) * 512 + t;
        int n    = gid >> 3;
        int head = gid & 7;
        if (n >= N_NODES) return;

        float xv[5];
#pragma unroll
        for (int k = 0; k < 5; ++k) xv[k] = x[n * 5 + k];

        float as = 0.f, ad = 0.f;
#pragma unroll
        for (int j = 0; j < 8; ++j) {
            int c = head * 8 + j;
            float acc = 0.f;
#pragma unroll
            for (int k = 0; k < 5; ++k) acc += xv[k] * W1[k * 64 + c];
            as += acc * a_src1[c];
            ad += acc * a_dst1[c];
        }
        as1h[n * 8 + head] = __float2half(as * LOG2E);
        ad1[n * 8 + head] = ad * LOG2E;

        if (head == 0) {                // padded fp16 x row: 8 halves = 16 B
            __half2 p0 = __halves2half2(__float2half(xv[0]), __float2half(xv[1]));
            __half2 p1 = __halves2half2(__float2half(xv[2]), __float2half(xv[3]));
            __half2 p2 = __halves2half2(__float2half(xv[4]), __float2half(0.f));
            __half2 p3 = __halves2half2(__float2half(0.f), __float2half(0.f));
            __half2* xp = (__half2*)&xh[(size_t)n * 8];
            xp[0] = p0; xp[1] = p1; xp[2] = p2; xp[3] = p3;
        }
        return;
    }

    // ---------- routing half ----------
    int blk = blockIdx.x;
    int base = blk * TP + t * 4;
    bool act = base < N_EDGES;           // tail block: exact multiple of 4
    lcnt[t] = 0; lcnt[t + 512] = 0;
    __syncthreads();

    nt_int4 s4, d4;
    int myidx[4];
    if (act) {
        s4 = __builtin_nontemporal_load((const nt_int4*)(src + base));
        d4 = __builtin_nontemporal_load((const nt_int4*)(dst + base));
#pragma unroll
        for (int j = 0; j < 4; ++j)
            myidx[j] = atomicAdd(&lcnt[d4[j] >> CBBITS], 1);
    }
    __syncthreads();

    // exclusive scan over 1024 bins, 2/thread (thread t owns bins 2t,2t+1)
    int b0 = lcnt[t * 2], b1 = lcnt[t * 2 + 1];
    int local = b0 + b1;
    int ln = t & 63, w = t >> 6;
    int sc = local;
#pragma unroll
    for (int off = 1; off < 64; off <<= 1) {
        int u = __shfl_up(sc, off, 64);
        if (ln >= off) sc += u;
    }
    if (ln == 63) wred[w] = sc;          // per-wave total
    __syncthreads();
    if (t < 8) {                         // scan the 8 wave totals
        int v = wred[t], s = v;
#pragma unroll
        for (int off = 1; off < 8; off <<= 1) {
            int u = __shfl_up(s, off, 8);
            if ((t & 7) >= off) s += u;
        }
        wred[t] = s - v;                 // exclusive base per wave
    }
    __syncthreads();
    int run = wred[w] + sc - local;      // exclusive base of bin 2t
    lcnt[t * 2] = run; lcnt[t * 2 + 1] = run + b0;
    __syncthreads();

    if (act) {
#pragma unroll
        for (int j = 0; j < 4; ++j) {
            int d = d4[j];
            stage[lcnt[d >> CBBITS] + myidx[j]] =
                ((unsigned)(d & (CB - 1)) << 17) | (unsigned)s4[j];
        }
    }
    __syncthreads();

    // append this block's 2 bins per thread to the global bucket windows
#pragma unroll
    for (int q = 0; q < 2; ++q) {
        int bin  = t * 2 + q;
        int cnt  = q ? b1 : b0;
        int sbase = q ? run + b0 : run;
        if (bin < NCB && cnt > 0) {
            int gb = atomicAdd(&gcur[bin], cnt);
            unsigned* wp = pairs + (size_t)bin * WINB;
            for (int j = 0; j < cnt; ++j) {
                int p = gb + j;
                if (p < WINB) wp[p] = stage[sbase + j];   // overflow clamp p~0
            }
        }
    }
}

// ---------------- bucket-local CSR build (782 x 512) --------------------
// Reads the bucket's records as ONE dense coalesced segment (written by
// k_np's run-append), histograms, scans, scatters in LDS, dumps ssrc.
__global__ void __launch_bounds__(512) k_csr(
        const int* __restrict__ gcur, const unsigned* __restrict__ pairs,
        int* __restrict__ rbeg, int* __restrict__ rend, int* __restrict__ ssrc) {
    __shared__ unsigned stIn[WINB];      // 10.25 KB
    __shared__ int stOut[WINB];          // 10.25 KB
    __shared__ int lcnt[CB], lofs[CB], lcur[CB];
    __shared__ int wsum[2];
    int B = blockIdx.x, t = threadIdx.x;
    int nvalid = min(CB, N_NODES - B * CB);
    int obase = B * WINB;

    if (t < CB) {
        lcnt[t] = (t < nvalid) ? 1 : 0;   // self-loop pre-count
        lcur[t] = 1;                      // slot 0 = self-loop
    }
    __syncthreads();

    int m = min(gcur[B], WINB);          // records routed to this bucket

    // dense coalesced load + histogram
    for (int i = t; i < m; i += 512) {
        unsigned r = pairs[(size_t)B * WINB + i];
        stIn[i] = r;
        atomicAdd(&lcnt[r >> 17], 1);
    }
    __syncthreads();

    // exclusive scan over 128 bins (first 2 waves carry data)
    int v = (t < CB) ? lcnt[t] : 0;
    int ln = t & 63, wv = t >> 6;
    int sc = v;
#pragma unroll
    for (int off = 1; off < 64; off <<= 1) {
        int u = __shfl_up(sc, off, 64);
        if (ln >= off) sc += u;
    }
    if (ln == 63 && wv < 2) wsum[wv] = sc;
    __syncthreads();
    int wbase = (wv == 1) ? wsum[0] : 0;
    int ex = wbase + sc - v;
    if (t < CB) {
        lofs[t] = ex;
        int gi = B * CB + t;
        if (gi < N_NODES) {
            rbeg[gi] = obase + ex;
            rend[gi] = obase + ex + v;
            stOut[ex] = gi;               // self-loop record, slot 0
        }
    }
    __syncthreads();

    // scatter into final CSR order (LDS -> LDS)
    for (int k = t; k < m; k += 512) {
        unsigned p = stIn[k];
        int dl = p >> 17;
        int idx = atomicAdd(&lcur[dl], 1);
        stOut[lofs[dl] + idx] = (int)(p & 0x1FFFF);
    }
    __syncthreads();

    // coalesced dump
    int tot = m + nvalid;
    for (int i = t; i < tot; i += 512) ssrc[obase + i] = stOut[i];
}

// ---------------- layer 1 gather + softmax (loop only) ------------------
// 16 lanes per dst (4 dsts/wave -> 25K waves), lane16 = (e = bit3 edge
// slot 0..1, h = lane&7 head). Stores normalized per-(dst,head)
// alpha-weighted x-sums as 5 SoA planes.
__global__ void __launch_bounds__(256) k_gather1(
        const int* __restrict__ rbeg, const int* __restrict__ rend,
        const int* __restrict__ ssrc, const float4* __restrict__ xh4,
        const __half* __restrict__ as1h, const float* __restrict__ ad1,
        float* __restrict__ xsbuf) {
    int gtid = blockIdx.x * blockDim.x + threadIdx.x;
    int d      = gtid >> 4;
    int lane16 = threadIdx.x & 15;
    if (d >= N_NODES) return;
    int e = lane16 >> 3;       // edge slot (0..1)
    int h = lane16 & 7;        // head

    int beg = rbeg[d], end = rend[d];
    float adv = ad1[d * 8 + h];                // pre-scaled by log2e
    float c0 = 0.f, c1 = 0.f, c2 = 0.f, c3 = 0.f, c4 = 0.f, den = 0.f;

    for (int k = beg; k < end; k += 4) {       // 2 predicated 2-edge groups
        int kA = k + e, kB = k + 2 + e;
        bool vA = kA < end, vB = kB < end;
        int sA = ssrc[vA ? kA : beg];
        int sB = ssrc[vB ? kB : beg];
        float eA = __half2float(as1h[sA * 8 + h]);
        float eB = __half2float(as1h[sB * 8 + h]);
        float4 xA = xh4[sA];                   // 8 halves: x0..x4,pad
        float4 xB = xh4[sB];
        float tA = eA + adv; tA = fmaxf(tA, NEG_SLOPE * tA);
        float tB = eB + adv; tB = fmaxf(tB, NEG_SLOPE * tB);
        float wA = vA ? __builtin_amdgcn_exp2f(tA) : 0.f;
        float wB = vB ? __builtin_amdgcn_exp2f(tB) : 0.f;
        float2 A01 = __half22float2(*(__half2*)&xA.x);
        float2 A23 = __half22float2(*(__half2*)&xA.y);
        float2 A4_ = __half22float2(*(__half2*)&xA.z);
        float2 B01 = __half22float2(*(__half2*)&xB.x);
        float2 B23 = __half22float2(*(__half2*)&xB.y);
        float2 B4_ = __half22float2(*(__half2*)&xB.z);
        c0 += wA * A01.x + wB * B01.x;
        c1 += wA * A01.y + wB * B01.y;
        c2 += wA * A23.x + wB * B23.x;
        c3 += wA * A23.y + wB * B23.y;
        c4 += wA * A4_.x + wB * B4_.x;
        den += wA + wB;
    }

    // reduce across the 2 edge slots (lane bit 3 — stays in 16-lane group)
#define REDH(x) x += __shfl_xor(x, 8, 64);
    REDH(c0) REDH(c1) REDH(c2) REDH(c3) REDH(c4) REDH(den)
#undef REDH

    if (e == 0) {                              // one lane per (dst, head)
        float inv = 1.f / den;                 // den>0 (self-loop guarantees)
        size_t idx = (size_t)d * 8 + h;
        xsbuf[idx]          = c0 * inv;
        xsbuf[N8 + idx]     = c1 * inv;
        xsbuf[2 * N8 + idx] = c2 * inv;
        xsbuf[3 * N8 + idx] = c3 * inv;
        xsbuf[4 * N8 + idx] = c4 * inv;
    }
}

// ---------------- per-dst epilogue: W1 + ELU + W2 + logits --------------
// 64 lanes = 8 dsts x 8 heads, SoA coalesced xsbuf reads. Layer-2 logits
// stored pre-scaled by log2e so k_gather2 uses raw exp2.
__global__ void __launch_bounds__(256) k_rec(
        const float* __restrict__ xsbuf, const float* __restrict__ b1,
        const float* __restrict__ W1, const float* __restrict__ W2,
        const float* __restrict__ a_src2, const float* __restrict__ a_dst2,
        float4* __restrict__ rec) {
    int gtid = blockIdx.x * blockDim.x + threadIdx.x;
    int d = gtid >> 3;
    int h = gtid & 7;
    if (d >= N_NODES) return;

    size_t idx = (size_t)d * 8 + h;
    float xs[5] = { xsbuf[idx], xsbuf[N8 + idx], xsbuf[2 * N8 + idx],
                    xsbuf[3 * N8 + idx], xsbuf[4 * N8 + idx] };

    // h = xs * W1 + b1 — this head's 8 channels, fp32
    float4 hA = ((const float4*)b1)[2 * h];
    float4 hB = ((const float4*)b1)[2 * h + 1];
#pragma unroll
    for (int c = 0; c < 5; ++c) {
        float xc = xs[c];
        float4 wA = *(const float4*)(W1 + c * 64 + 8 * h);
        float4 wB = *(const float4*)(W1 + c * 64 + 8 * h + 4);
        hA.x += xc * wA.x; hA.y += xc * wA.y; hA.z += xc * wA.z; hA.w += xc * wA.w;
        hB.x += xc * wB.x; hB.y += xc * wB.y; hB.z += xc * wB.z; hB.w += xc * wB.w;
    }
    float v0 = hA.x, v1 = hA.y, v2 = hA.z, v3 = hA.w;
    float v4 = hB.x, v5 = hB.y, v6 = hB.z, v7 = hB.w;
    v0 = (v0 > 0.f) ? v0 : (__expf(v0) - 1.f); // ELU
    v1 = (v1 > 0.f) ? v1 : (__expf(v1) - 1.f);
    v2 = (v2 > 0.f) ? v2 : (__expf(v2) - 1.f);
    v3 = (v3 > 0.f) ? v3 : (__expf(v3) - 1.f);
    v4 = (v4 > 0.f) ? v4 : (__expf(v4) - 1.f);
    v5 = (v5 > 0.f) ? v5 : (__expf(v5) - 1.f);
    v6 = (v6 > 0.f) ? v6 : (__expf(v6) - 1.f);
    v7 = (v7 > 0.f) ? v7 : (__expf(v7) - 1.f);

    // fused layer-2 transform: this lane's 8 channels (head h) x W2[64,2]
    const float4* w4 = (const float4*)(W2 + h * 16);
    float4 wq0 = w4[0], wq1 = w4[1], wq2 = w4[2], wq3 = w4[3];
    float h20 = v0 * wq0.x + v1 * wq0.z + v2 * wq1.x + v3 * wq1.z
              + v4 * wq2.x + v5 * wq2.z + v6 * wq3.x + v7 * wq3.z;
    float h21 = v0 * wq0.y + v1 * wq0.w + v2 * wq1.y + v3 * wq1.w
              + v4 * wq2.y + v5 * wq2.w + v6 * wq3.y + v7 * wq3.w;
    // reduce across the 8 heads (lane bits 0..2)
    h20 += __shfl_xor(h20, 1, 64); h20 += __shfl_xor(h20, 2, 64); h20 += __shfl_xor(h20, 4, 64);
    h21 += __shfl_xor(h21, 1, 64); h21 += __shfl_xor(h21, 2, 64); h21 += __shfl_xor(h21, 4, 64);

    if (h == 0) {
        float as2v = (h20 * a_src2[0] + h21 * a_src2[1]) * LOG2E;
        float ad2v = (h20 * a_dst2[0] + h21 * a_dst2[1]) * LOG2E;
        rec[d] = make_float4(h20, h21, as2v, ad2v);
    }
}

// ---------------- layer 2: per-dst gather + log_softmax -----------------
// 8 lanes per dst (8 dsts/wave). rec.z/.w pre-scaled by log2e.
__global__ void __launch_bounds__(256) k_gather2(
        const int* __restrict__ rbeg, const int* __restrict__ rend,
        const int* __restrict__ ssrc, const float4* __restrict__ rec,
        const float* __restrict__ b2, float* __restrict__ out) {
    int gtid = blockIdx.x * blockDim.x + threadIdx.x;
    int d    = gtid >> 3;
    int lane = threadIdx.x & 7;
    if (d >= N_NODES) return;

    int beg = rbeg[d], end = rend[d];
    float adv = rec[d].w;
    float n0 = 0.f, n1 = 0.f, den = 0.f;
    for (int k = beg; k < end; k += 8) {
        int ki = k + lane;
        bool v = ki < end;
        int s = ssrc[v ? ki : beg];
        float4 r = rec[s];
        float t = r.z + adv; t = fmaxf(t, NEG_SLOPE * t);
        float w = v ? __builtin_amdgcn_exp2f(t) : 0.f;
        n0 += w * r.x; n1 += w * r.y; den += w;
    }
#pragma unroll
    for (int off = 1; off < 8; off <<= 1) {
        n0  += __shfl_xor(n0,  off, 8);
        n1  += __shfl_xor(n1,  off, 8);
        den += __shfl_xor(den, off, 8);
    }
    if (lane == 0) {
        float o0 = n0 / den + b2[0];
        float o1 = n1 / den + b2[1];
        float m  = fmaxf(o0, o1);
        float lse = m + __logf(__expf(o0 - m) + __expf(o1 - m));
        *(float2*)(out + (size_t)d * 2) = make_float2(o0 - lse, o1 - lse);
    }
}

extern "C" void kernel_launch(void* const* d_in, const int* in_sizes, int n_in,
                              void* d_out, int out_size, void* d_ws, size_t ws_size,
                              hipStream_t stream) {
    const float* x      = (const float*)d_in[0];
    const int*   ei     = (const int*)d_in[1];     // [2, E] int32
    const float* W1     = (const float*)d_in[2];
    const float* a_src1 = (const float*)d_in[3];
    const float* a_dst1 = (const float*)d_in[4];
    const float* b1     = (const float*)d_in[5];
    const float* W2     = (const float*)d_in[6];
    const float* a_src2 = (const float*)d_in[7];
    const float* a_dst2 = (const float*)d_in[8];
    const float* b2     = (const float*)d_in[9];
    float* out = (float*)d_out;

    const int* src = ei;
    const int* dst = ei + N_EDGES;

    // ---- workspace layout (~33 MB). REGION rg holds gcur+pairs during
    // the sort, then is REUSED as xsbuf (16 MB) by gather1/rec — both are
    // dead after k_csr. gcur is zeroed via hipMemsetAsync; every other
    // byte read downstream is written by a kernel first.
    int* rbeg   = (int*)d_ws;                                   // N
    int* rend   = rbeg + N_NODES;                               // N
    int* ssrc   = rend + N_NODES;                               // NCB*WINB (8 MB)
    uintptr_t pp = ((uintptr_t)(ssrc + (size_t)NCB * WINB) + 255) & ~(uintptr_t)255;
    float4*   rec  = (float4*)pp;                               // N float4 (1.6 MB)
    float*    ad1  = (float*)(rec + N_NODES);                   // N*8 fp32 (3.2 MB)
    __half*   as1h = (__half*)(ad1 + (size_t)N_NODES * 8);      // N*8 fp16 (1.6 MB)
    __half*   xh   = as1h + (size_t)N_NODES * 8;                // N*8 fp16 (1.6 MB)
    uintptr_t rg = ((uintptr_t)(xh + (size_t)N_NODES * 8) + 255) & ~(uintptr_t)255;
    int*      gcur  = (int*)rg;                                 // NCB ints (3.1 KB)
    unsigned* pairs = (unsigned*)(((uintptr_t)(gcur + NCB) + 255) & ~(uintptr_t)255); // NCB*WINB (8 MB)
    float*    xsbuf = (float*)rg;                               // 5*N8 fp32 (16 MB, overlays gcur+pairs)

    hipMemsetAsync(gcur, 0, NCB * sizeof(int), stream);
    k_np<<<NPB + NB_NODE1, 512, 0, stream>>>(src, dst, gcur, pairs,
                                             x, W1, a_src1, a_dst1,
                                             xh, as1h, ad1);
    k_csr<<<NCB, 512, 0, stream>>>(gcur, pairs, rbeg, rend, ssrc);
    k_gather1<<<(N_NODES * 16 + 255) / 256, 256, 0, stream>>>(rbeg, rend, ssrc,
                                                              (const float4*)xh,
                                                              as1h, ad1, xsbuf);
    k_rec<<<(N_NODES * 8 + 255) / 256, 256, 0, stream>>>(xsbuf, b1, W1, W2,
                                                         a_src2, a_dst2, rec);
    k_gather2<<<(N_NODES * 8 + 255) / 256, 256, 0, stream>>>(rbeg, rend, ssrc,
                                                             rec, b2, out);
}

// Round 13
// 153.889 us; speedup vs baseline: 1.1771x; 1.1771x over previous
//
#include <hip/hip_runtime.h>
#include <hip/hip_fp16.h>
#include <math.h>
#include <stdint.h>

#define N_NODES 100000
#define N_EDGES 1600000
#define NEG_SLOPE 0.2f
#define LOG2E 1.44269504088896340736f

#define CB     128                            // dst nodes per bucket
#define CBBITS 7
#define NCB    ((N_NODES + CB - 1) / CB)      // 782 buckets
#define TP     2048                           // edges per partition block
#define NPB    ((N_EDGES + TP - 1) / TP)      // 782 partition blocks
#define WINB   2560                           // fixed ssrc window per bucket (mean load 2174, +11 sigma)
#define NB_NODE1 ((N_NODES * 8 + 511) / 512)  // node1 blocks in fused kernel
#define N8     ((size_t)N_NODES * 8)
#define NTT    25                             // transpose tiles per dim

typedef int nt_int4 __attribute__((ext_vector_type(4)));

// ---------------- fused: block-radix partition + node transform ---------
// Blocks [0, NPB): edge partition (R11-proven: LDS rank-sort, coalesced
// ofs rows + pairs dump). Blocks [NPB, ...): node transform writing the
// PACKED per-src record nd[n] = {as[0..7] fp16 (log2e-scaled) | x0..x4
// fp16 pad} — 32 B. Both of gather1's per-edge loads then hit the SAME
// 64B line (halves L2 line-transactions vs split as1h/xh tables).
__global__ void __launch_bounds__(512) k_np(
        const int* __restrict__ src, const int* __restrict__ dst,
        int* __restrict__ ofs, unsigned* __restrict__ pairs,
        const float* __restrict__ x, const float* __restrict__ W1,
        const float* __restrict__ a_src1, const float* __restrict__ a_dst1,
        __half* __restrict__ nd, float* __restrict__ ad1) {
    __shared__ int lcnt[1024];           // bins (782 used): counts -> bases
    __shared__ unsigned stage[TP];       // 8 KB
    __shared__ int wred[8];
    int t = threadIdx.x;

    if (blockIdx.x >= NPB) {
        // ---------- node1 half ----------
        int gid  = (blockIdx.x - NPB) * 512 + t;
        int n    = gid >> 3;
        int head = gid & 7;
        if (n >= N_NODES) return;

        float xv[5];
#pragma unroll
        for (int k = 0; k < 5; ++k) xv[k] = x[n * 5 + k];

        float as = 0.f, ad = 0.f;
#pragma unroll
        for (int j = 0; j < 8; ++j) {
            int c = head * 8 + j;
            float acc = 0.f;
#pragma unroll
            for (int k = 0; k < 5; ++k) acc += xv[k] * W1[k * 64 + c];
            as += acc * a_src1[c];
            ad += acc * a_dst1[c];
        }
        nd[(size_t)n * 16 + head] = __float2half(as * LOG2E);   // 8 consecutive halves
        ad1[n * 8 + head] = ad * LOG2E;

        if (head == 0) {                // x chunk: halves 8..15 of the record
            __half2 p0 = __halves2half2(__float2half(xv[0]), __float2half(xv[1]));
            __half2 p1 = __halves2half2(__float2half(xv[2]), __float2half(xv[3]));
            __half2 p2 = __halves2half2(__float2half(xv[4]), __float2half(0.f));
            __half2 p3 = __halves2half2(__float2half(0.f), __float2half(0.f));
            __half2* xp = (__half2*)&nd[(size_t)n * 16 + 8];    // byte ofs n*32+16, 16B-aligned
            xp[0] = p0; xp[1] = p1; xp[2] = p2; xp[3] = p3;
        }
        return;
    }

    // ---------- partition half ----------
    int blk = blockIdx.x;
    int base = blk * TP + t * 4;
    bool act = base < N_EDGES;           // tail block: exact multiple of 4
    int nE = min(TP, N_EDGES - blk * TP);

    lcnt[t] = 0; lcnt[t + 512] = 0;
    __syncthreads();

    nt_int4 s4, d4;
    int myidx[4];
    if (act) {
        s4 = __builtin_nontemporal_load((const nt_int4*)(src + base));
        d4 = __builtin_nontemporal_load((const nt_int4*)(dst + base));
#pragma unroll
        for (int j = 0; j < 4; ++j)
            myidx[j] = atomicAdd(&lcnt[d4[j] >> CBBITS], 1);
    }
    __syncthreads();

    // exclusive scan over 1024 bins, 2/thread: wave-shuffle scan
    int b0 = lcnt[t * 2], b1 = lcnt[t * 2 + 1];
    int local = b0 + b1;
    int ln = t & 63, w = t >> 6;
    int sc = local;
#pragma unroll
    for (int off = 1; off < 64; off <<= 1) {
        int u = __shfl_up(sc, off, 64);
        if (ln >= off) sc += u;
    }
    if (ln == 63) wred[w] = sc;          // per-wave total
    __syncthreads();
    if (t < 8) {                         // scan the 8 wave totals
        int v = wred[t], s = v;
#pragma unroll
        for (int off = 1; off < 8; off <<= 1) {
            int u = __shfl_up(s, off, 8);
            if ((t & 7) >= off) s += u;
        }
        wred[t] = s - v;                 // exclusive base per wave
    }
    __syncthreads();
    int run = wred[w] + sc - local;      // exclusive prefix of this thread's 2 bins
    lcnt[t * 2] = run; lcnt[t * 2 + 1] = run + b0;
    int* orow = ofs + (size_t)blk * (NCB + 1);       // row-major, coalesced
    if (t * 2     <= NCB) orow[t * 2]     = run;
    if (t * 2 + 1 <= NCB) orow[t * 2 + 1] = run + b0;
    __syncthreads();

    if (act) {
#pragma unroll
        for (int j = 0; j < 4; ++j) {
            int d = d4[j];
            stage[lcnt[d >> CBBITS] + myidx[j]] =
                ((unsigned)(d & (CB - 1)) << 17) | (unsigned)s4[j];
        }
    }
    __syncthreads();
    for (int i = t; i < nE; i += 512)
        pairs[(size_t)blk * TP + i] = stage[i];      // coalesced dump
}

// ---------------- ofs transpose: [NPB][NCB+1] -> [NCB+1][NPB] -----------
__global__ void __launch_bounds__(256) k_tr(
        const int* __restrict__ ofs, int* __restrict__ ofsT) {
    __shared__ int tile[32][33];
    int bx = blockIdx.x % NTT;           // tile col over bins (NCB+1)
    int by = blockIdx.x / NTT;           // tile row over blocks (NPB)
    int tx = threadIdx.x & 31, ty = threadIdx.x >> 5;   // ty 0..7
#pragma unroll
    for (int i = 0; i < 4; ++i) {
        int r = by * 32 + ty + 8 * i;    // block index
        int c = bx * 32 + tx;            // bin index
        tile[ty + 8 * i][tx] = (r < NPB && c <= NCB)
                             ? ofs[(size_t)r * (NCB + 1) + c] : 0;
    }
    __syncthreads();
#pragma unroll
    for (int i = 0; i < 4; ++i) {
        int c = bx * 32 + ty + 8 * i;    // bin index
        int r = by * 32 + tx;            // block index
        if (c <= NCB && r < NPB)
            ofsT[(size_t)c * NPB + r] = tile[tx][ty + 8 * i];
    }
}

// ---------------- bucket-local CSR build (782 x 512) --------------------
// R11-proven: coalesced ofsT rows -> slice-count scan -> direct sliceId
// map -> independent record fetch -> LDS scatter -> coalesced dump.
__global__ void __launch_bounds__(512) k_csr(
        const int* __restrict__ ofsT, const unsigned* __restrict__ pairs,
        int* __restrict__ rbeg, int* __restrict__ rend, int* __restrict__ ssrc) {
    __shared__ unsigned stIn[WINB];      // 10.25 KB
    __shared__ int stOut[WINB];          // 10.25 KB
    __shared__ unsigned short sliceId[WINB];  // 5.12 KB
    __shared__ int o0s[NPB];             // slice start within its block seg
    __shared__ int cns[1026];            // slice-count scan (pad to 1024)
    __shared__ int lcnt[CB], lofs[CB], lcur[CB];
    __shared__ int wsum[2];
    __shared__ int wred[8];
    int B = blockIdx.x, t = threadIdx.x;
    int nvalid = min(CB, N_NODES - B * CB);
    int obase = B * WINB;

    for (int s = t; s < NPB; s += 512) {
        int o0 = ofsT[(size_t)B       * NPB + s];
        int o1 = ofsT[(size_t)(B + 1) * NPB + s];
        o0s[s] = o0;
        cns[s] = o1 - o0;
    }
    for (int s = NPB + t; s < 1024; s += 512) cns[s] = 0;   // pad
    if (t < CB) {
        lcnt[t] = (t < nvalid) ? 1 : 0;   // self-loop pre-count
        lcur[t] = 1;                      // slot 0 = self-loop
    }
    __syncthreads();

    // exclusive scan over 1024 slice counts, 2/thread
    int a0 = cns[t * 2], a1 = cns[t * 2 + 1];
    int local = a0 + a1;
    int ln = t & 63, w = t >> 6;
    int sc2 = local;
#pragma unroll
    for (int off = 1; off < 64; off <<= 1) {
        int u = __shfl_up(sc2, off, 64);
        if (ln >= off) sc2 += u;
    }
    if (ln == 63) wred[w] = sc2;
    __syncthreads();
    if (t < 8) {
        int v = wred[t], s = v;
#pragma unroll
        for (int off = 1; off < 8; off <<= 1) {
            int u = __shfl_up(s, off, 8);
            if ((t & 7) >= off) s += u;
        }
        wred[t] = s - v;
    }
    __syncthreads();
    int run = wred[w] + sc2 - local;
    cns[t * 2] = run; cns[t * 2 + 1] = run + a0;   // exclusive bases
    __syncthreads();
    int m = cns[NPB];                    // total records (pads are zero)

    // direct slice map: owner writes its records' slice id (~2.8 each)
    for (int s = t; s < NPB; s += 512) {
        int j0 = cns[s], j1 = cns[s + 1];
        for (int j = j0; j < j1; ++j) sliceId[j] = (unsigned short)s;
    }
    __syncthreads();

    // record fetch: one LDS read for slice, independent global load
    for (int i = t; i < m; i += 512) {
        int s = sliceId[i];
        unsigned r = pairs[(size_t)s * TP + o0s[s] + (i - cns[s])];
        stIn[i] = r;
        atomicAdd(&lcnt[r >> 17], 1);
    }
    __syncthreads();

    // exclusive scan over 128 bins (first 2 waves carry data)
    int v = (t < CB) ? lcnt[t] : 0;
    int wv = t >> 6;
    int sc = v;
#pragma unroll
    for (int off = 1; off < 64; off <<= 1) {
        int u = __shfl_up(sc, off, 64);
        if (ln >= off) sc += u;
    }
    if (ln == 63 && wv < 2) wsum[wv] = sc;
    __syncthreads();
    int wbase = (wv == 1) ? wsum[0] : 0;
    int ex = wbase + sc - v;
    if (t < CB) {
        lofs[t] = ex;
        int gi = B * CB + t;
        if (gi < N_NODES) {
            rbeg[gi] = obase + ex;
            rend[gi] = obase + ex + v;
            stOut[ex] = gi;               // self-loop record, slot 0
        }
    }
    __syncthreads();

    // scatter into final CSR order (LDS -> LDS)
    for (int k = t; k < m; k += 512) {
        unsigned p = stIn[k];
        int dl = p >> 17;
        int idx = atomicAdd(&lcur[dl], 1);
        stOut[lofs[dl] + idx] = (int)(p & 0x1FFFF);
    }
    __syncthreads();

    // coalesced dump
    int tot = m + nvalid;
    for (int i = t; i < tot; i += 512) ssrc[obase + i] = stOut[i];
}

// ---------------- layer 1 gather + softmax (loop only) ------------------
// 16 lanes per dst (4 dsts/wave), lane16 = (e = bit3 edge slot 0..1,
// h = lane&7 head). PACKED nd record: as load (2B) and x load (16B) hit
// the same 64B line — per-edge L2 line-touches halved vs split tables.
__global__ void __launch_bounds__(256) k_gather1(
        const int* __restrict__ rbeg, const int* __restrict__ rend,
        const int* __restrict__ ssrc, const __half* __restrict__ nd,
        const float* __restrict__ ad1, float* __restrict__ xsbuf) {
    int gtid = blockIdx.x * blockDim.x + threadIdx.x;
    int d      = gtid >> 4;
    int lane16 = threadIdx.x & 15;
    if (d >= N_NODES) return;
    int e = lane16 >> 3;       // edge slot (0..1)
    int h = lane16 & 7;        // head

    int beg = rbeg[d], end = rend[d];
    float adv = ad1[d * 8 + h];                // pre-scaled by log2e
    float c0 = 0.f, c1 = 0.f, c2 = 0.f, c3 = 0.f, c4 = 0.f, den = 0.f;

    for (int k = beg; k < end; k += 4) {       // 2 predicated 2-edge groups
        int kA = k + e, kB = k + 2 + e;
        bool vA = kA < end, vB = kB < end;
        int sA = ssrc[vA ? kA : beg];
        int sB = ssrc[vB ? kB : beg];
        float eA = __half2float(nd[(size_t)sA * 16 + h]);
        float eB = __half2float(nd[(size_t)sB * 16 + h]);
        float4 xA = *(const float4*)(nd + (size_t)sA * 16 + 8);  // same line as eA
        float4 xB = *(const float4*)(nd + (size_t)sB * 16 + 8);
        float tA = eA + adv; tA = fmaxf(tA, NEG_SLOPE * tA);
        float tB = eB + adv; tB = fmaxf(tB, NEG_SLOPE * tB);
        float wA = vA ? __builtin_amdgcn_exp2f(tA) : 0.f;
        float wB = vB ? __builtin_amdgcn_exp2f(tB) : 0.f;
        float2 A01 = __half22float2(*(__half2*)&xA.x);
        float2 A23 = __half22float2(*(__half2*)&xA.y);
        float2 A4_ = __half22float2(*(__half2*)&xA.z);
        float2 B01 = __half22float2(*(__half2*)&xB.x);
        float2 B23 = __half22float2(*(__half2*)&xB.y);
        float2 B4_ = __half22float2(*(__half2*)&xB.z);
        c0 += wA * A01.x + wB * B01.x;
        c1 += wA * A01.y + wB * B01.y;
        c2 += wA * A23.x + wB * B23.x;
        c3 += wA * A23.y + wB * B23.y;
        c4 += wA * A4_.x + wB * B4_.x;
        den += wA + wB;
    }

    // reduce across the 2 edge slots (lane bit 3 — stays in 16-lane group)
#define REDH(x) x += __shfl_xor(x, 8, 64);
    REDH(c0) REDH(c1) REDH(c2) REDH(c3) REDH(c4) REDH(den)
#undef REDH

    if (e == 0) {                              // one lane per (dst, head)
        float inv = 1.f / den;                 // den>0 (self-loop guarantees)
        size_t idx = (size_t)d * 8 + h;
        xsbuf[idx]          = c0 * inv;
        xsbuf[N8 + idx]     = c1 * inv;
        xsbuf[2 * N8 + idx] = c2 * inv;
        xsbuf[3 * N8 + idx] = c3 * inv;
        xsbuf[4 * N8 + idx] = c4 * inv;
    }
}

// ---------------- per-dst epilogue: W1 + ELU + W2 + logits --------------
__global__ void __launch_bounds__(256) k_rec(
        const float* __restrict__ xsbuf, const float* __restrict__ b1,
        const float* __restrict__ W1, const float* __restrict__ W2,
        const float* __restrict__ a_src2, const float* __restrict__ a_dst2,
        float4* __restrict__ rec) {
    int gtid = blockIdx.x * blockDim.x + threadIdx.x;
    int d = gtid >> 3;
    int h = gtid & 7;
    if (d >= N_NODES) return;

    size_t idx = (size_t)d * 8 + h;
    float xs[5] = { xsbuf[idx], xsbuf[N8 + idx], xsbuf[2 * N8 + idx],
                    xsbuf[3 * N8 + idx], xsbuf[4 * N8 + idx] };

    // h = xs * W1 + b1 — this head's 8 channels, fp32
    float4 hA = ((const float4*)b1)[2 * h];
    float4 hB = ((const float4*)b1)[2 * h + 1];
#pragma unroll
    for (int c = 0; c < 5; ++c) {
        float xc = xs[c];
        float4 wA = *(const float4*)(W1 + c * 64 + 8 * h);
        float4 wB = *(const float4*)(W1 + c * 64 + 8 * h + 4);
        hA.x += xc * wA.x; hA.y += xc * wA.y; hA.z += xc * wA.z; hA.w += xc * wA.w;
        hB.x += xc * wB.x; hB.y += xc * wB.y; hB.z += xc * wB.z; hB.w += xc * wB.w;
    }
    float v0 = hA.x, v1 = hA.y, v2 = hA.z, v3 = hA.w;
    float v4 = hB.x, v5 = hB.y, v6 = hB.z, v7 = hB.w;
    v0 = (v0 > 0.f) ? v0 : (__expf(v0) - 1.f); // ELU
    v1 = (v1 > 0.f) ? v1 : (__expf(v1) - 1.f);
    v2 = (v2 > 0.f) ? v2 : (__expf(v2) - 1.f);
    v3 = (v3 > 0.f) ? v3 : (__expf(v3) - 1.f);
    v4 = (v4 > 0.f) ? v4 : (__expf(v4) - 1.f);
    v5 = (v5 > 0.f) ? v5 : (__expf(v5) - 1.f);
    v6 = (v6 > 0.f) ? v6 : (__expf(v6) - 1.f);
    v7 = (v7 > 0.f) ? v7 : (__expf(v7) - 1.f);

    // fused layer-2 transform: this lane's 8 channels (head h) x W2[64,2]
    const float4* w4 = (const float4*)(W2 + h * 16);
    float4 wq0 = w4[0], wq1 = w4[1], wq2 = w4[2], wq3 = w4[3];
    float h20 = v0 * wq0.x + v1 * wq0.z + v2 * wq1.x + v3 * wq1.z
              + v4 * wq2.x + v5 * wq2.z + v6 * wq3.x + v7 * wq3.z;
    float h21 = v0 * wq0.y + v1 * wq0.w + v2 * wq1.y + v3 * wq1.w
              + v4 * wq2.y + v5 * wq2.w + v6 * wq3.y + v7 * wq3.w;
    // reduce across the 8 heads (lane bits 0..2)
    h20 += __shfl_xor(h20, 1, 64); h20 += __shfl_xor(h20, 2, 64); h20 += __shfl_xor(h20, 4, 64);
    h21 += __shfl_xor(h21, 1, 64); h21 += __shfl_xor(h21, 2, 64); h21 += __shfl_xor(h21, 4, 64);

    if (h == 0) {
        float as2v = (h20 * a_src2[0] + h21 * a_src2[1]) * LOG2E;
        float ad2v = (h20 * a_dst2[0] + h21 * a_dst2[1]) * LOG2E;
        rec[d] = make_float4(h20, h21, as2v, ad2v);
    }
}

// ---------------- layer 2: per-dst gather + log_softmax -----------------
__global__ void __launch_bounds__(256) k_gather2(
        const int* __restrict__ rbeg, const int* __restrict__ rend,
        const int* __restrict__ ssrc, const float4* __restrict__ rec,
        const float* __restrict__ b2, float* __restrict__ out) {
    int gtid = blockIdx.x * blockDim.x + threadIdx.x;
    int d    = gtid >> 3;
    int lane = threadIdx.x & 7;
    if (d >= N_NODES) return;

    int beg = rbeg[d], end = rend[d];
    float adv = rec[d].w;
    float n0 = 0.f, n1 = 0.f, den = 0.f;
    for (int k = beg; k < end; k += 8) {
        int ki = k + lane;
        bool v = ki < end;
        int s = ssrc[v ? ki : beg];
        float4 r = rec[s];
        float t = r.z + adv; t = fmaxf(t, NEG_SLOPE * t);
        float w = v ? __builtin_amdgcn_exp2f(t) : 0.f;
        n0 += w * r.x; n1 += w * r.y; den += w;
    }
#pragma unroll
    for (int off = 1; off < 8; off <<= 1) {
        n0  += __shfl_xor(n0,  off, 8);
        n1  += __shfl_xor(n1,  off, 8);
        den += __shfl_xor(den, off, 8);
    }
    if (lane == 0) {
        float o0 = n0 / den + b2[0];
        float o1 = n1 / den + b2[1];
        float m  = fmaxf(o0, o1);
        float lse = m + __logf(__expf(o0 - m) + __expf(o1 - m));
        *(float2*)(out + (size_t)d * 2) = make_float2(o0 - lse, o1 - lse);
    }
}

extern "C" void kernel_launch(void* const* d_in, const int* in_sizes, int n_in,
                              void* d_out, int out_size, void* d_ws, size_t ws_size,
                              hipStream_t stream) {
    const float* x      = (const float*)d_in[0];
    const int*   ei     = (const int*)d_in[1];     // [2, E] int32
    const float* W1     = (const float*)d_in[2];
    const float* a_src1 = (const float*)d_in[3];
    const float* a_dst1 = (const float*)d_in[4];
    const float* b1     = (const float*)d_in[5];
    const float* W2     = (const float*)d_in[6];
    const float* a_src2 = (const float*)d_in[7];
    const float* a_dst2 = (const float*)d_in[8];
    const float* b2     = (const float*)d_in[9];
    float* out = (float*)d_out;

    const int* src = ei;
    const int* dst = ei + N_EDGES;

    // ---- workspace layout (~36 MB). REGION rg holds ofs+ofsT+pairs
    // during the sort, then is REUSED as xsbuf (16 MB) by gather1/rec —
    // all three are dead after k_csr. Everything written before read.
    int* rbeg   = (int*)d_ws;                                   // N
    int* rend   = rbeg + N_NODES;                               // N
    int* ssrc   = rend + N_NODES;                               // NCB*WINB (8 MB)
    uintptr_t pp = ((uintptr_t)(ssrc + (size_t)NCB * WINB) + 255) & ~(uintptr_t)255;
    float4*   rec  = (float4*)pp;                               // N float4 (1.6 MB)
    float*    ad1  = (float*)(rec + N_NODES);                   // N*8 fp32 (3.2 MB)
    __half*   nd   = (__half*)(ad1 + (size_t)N_NODES * 8);      // N*16 fp16 (3.2 MB, packed as+x)
    uintptr_t rg = ((uintptr_t)(nd + (size_t)N_NODES * 16) + 255) & ~(uintptr_t)255;
    int*      ofs   = (int*)rg;                                 // NPB*(NCB+1) (2.45 MB)
    int*      ofsT  = ofs + (size_t)NPB * (NCB + 1);            // (NCB+1)*NPB (2.45 MB)
    unsigned* pairs = (unsigned*)(ofsT + (size_t)(NCB + 1) * NPB); // E (6.4 MB)
    float*    xsbuf = (float*)rg;                               // 5*N8 fp32 (16 MB, overlays sort bufs)

    k_np<<<NPB + NB_NODE1, 512, 0, stream>>>(src, dst, ofs, pairs,
                                             x, W1, a_src1, a_dst1,
                                             nd, ad1);
    k_tr<<<NTT * NTT, 256, 0, stream>>>(ofs, ofsT);
    k_csr<<<NCB, 512, 0, stream>>>(ofsT, pairs, rbeg, rend, ssrc);
    k_gather1<<<(N_NODES * 16 + 255) / 256, 256, 0, stream>>>(rbeg, rend, ssrc,
                                                              nd, ad1, xsbuf);
    k_rec<<<(N_NODES * 8 + 255) / 256, 256, 0, stream>>>(xsbuf, b1, W1, W2,
                                                         a_src2, a_dst2, rec);
    k_gather2<<<(N_NODES * 8 + 255) / 256, 256, 0, stream>>>(rbeg, rend, ssrc,
                                                             rec, b2, out);
}

// Round 14
// 152.646 us; speedup vs baseline: 1.1867x; 1.0081x over previous
//
#include <hip/hip_runtime.h>
#include <hip/hip_fp16.h>
#include <math.h>
#include <stdint.h>

#define N_NODES 100000
#define N_EDGES 1600000
#define NEG_SLOPE 0.2f
#define LOG2E 1.44269504088896340736f

#define CB     128                            // dst nodes per bucket
#define CBBITS 7
#define NCB    ((N_NODES + CB - 1) / CB)      // 782 buckets
#define TP     2048                           // edges per partition block
#define NPB    ((N_EDGES + TP - 1) / TP)      // 782 partition blocks
#define WINB   2560                           // fixed ssrc window per bucket (mean load 2174, +11 sigma)
#define NB_NODE1 ((N_NODES * 8 + 511) / 512)  // node1 blocks in fused kernel

typedef int nt_int4 __attribute__((ext_vector_type(4)));

// ---------------- fused: block-radix partition + node transform ---------
// Blocks [0, NPB): edge partition (LDS rank-sort, coalesced ofs rows +
// pairs dump). Blocks [NPB, ...): node transform writing the PACKED
// per-src record nd[n] = {as[0..7] fp16 (log2e-scaled) | x0..x4 fp16
// pad} — 32 B, so gather1's two per-edge loads share one 64B line.
__global__ void __launch_bounds__(512) k_np(
        const int* __restrict__ src, const int* __restrict__ dst,
        int* __restrict__ ofs, unsigned* __restrict__ pairs,
        const float* __restrict__ x, const float* __restrict__ W1,
        const float* __restrict__ a_src1, const float* __restrict__ a_dst1,
        __half* __restrict__ nd, float* __restrict__ ad1) {
    __shared__ int lcnt[1024];           // bins (782 used): counts -> bases
    __shared__ unsigned stage[TP];       // 8 KB
    __shared__ int wred[8];
    int t = threadIdx.x;

    if (blockIdx.x >= NPB) {
        // ---------- node1 half ----------
        int gid  = (blockIdx.x - NPB) * 512 + t;
        int n    = gid >> 3;
        int head = gid & 7;
        if (n >= N_NODES) return;

        float xv[5];
#pragma unroll
        for (int k = 0; k < 5; ++k) xv[k] = x[n * 5 + k];

        float as = 0.f, ad = 0.f;
#pragma unroll
        for (int j = 0; j < 8; ++j) {
            int c = head * 8 + j;
            float acc = 0.f;
#pragma unroll
            for (int k = 0; k < 5; ++k) acc += xv[k] * W1[k * 64 + c];
            as += acc * a_src1[c];
            ad += acc * a_dst1[c];
        }
        nd[(size_t)n * 16 + head] = __float2half(as * LOG2E);   // 8 consecutive halves
        ad1[n * 8 + head] = ad * LOG2E;

        if (head == 0) {                // x chunk: halves 8..15 of the record
            __half2 p0 = __halves2half2(__float2half(xv[0]), __float2half(xv[1]));
            __half2 p1 = __halves2half2(__float2half(xv[2]), __float2half(xv[3]));
            __half2 p2 = __halves2half2(__float2half(xv[4]), __float2half(0.f));
            __half2 p3 = __halves2half2(__float2half(0.f), __float2half(0.f));
            __half2* xp = (__half2*)&nd[(size_t)n * 16 + 8];    // byte ofs n*32+16, 16B-aligned
            xp[0] = p0; xp[1] = p1; xp[2] = p2; xp[3] = p3;
        }
        return;
    }

    // ---------- partition half ----------
    int blk = blockIdx.x;
    int base = blk * TP + t * 4;
    bool act = base < N_EDGES;           // tail block: exact multiple of 4
    int nE = min(TP, N_EDGES - blk * TP);

    lcnt[t] = 0; lcnt[t + 512] = 0;
    __syncthreads();

    nt_int4 s4, d4;
    int myidx[4];
    if (act) {
        s4 = __builtin_nontemporal_load((const nt_int4*)(src + base));
        d4 = __builtin_nontemporal_load((const nt_int4*)(dst + base));
#pragma unroll
        for (int j = 0; j < 4; ++j)
            myidx[j] = atomicAdd(&lcnt[d4[j] >> CBBITS], 1);
    }
    __syncthreads();

    // exclusive scan over 1024 bins, 2/thread: wave-shuffle scan
    int b0 = lcnt[t * 2], b1 = lcnt[t * 2 + 1];
    int local = b0 + b1;
    int ln = t & 63, w = t >> 6;
    int sc = local;
#pragma unroll
    for (int off = 1; off < 64; off <<= 1) {
        int u = __shfl_up(sc, off, 64);
        if (ln >= off) sc += u;
    }
    if (ln == 63) wred[w] = sc;          // per-wave total
    __syncthreads();
    if (t < 8) {                         // scan the 8 wave totals
        int v = wred[t], s = v;
#pragma unroll
        for (int off = 1; off < 8; off <<= 1) {
            int u = __shfl_up(s, off, 8);
            if ((t & 7) >= off) s += u;
        }
        wred[t] = s - v;                 // exclusive base per wave
    }
    __syncthreads();
    int run = wred[w] + sc - local;      // exclusive prefix of this thread's 2 bins
    lcnt[t * 2] = run; lcnt[t * 2 + 1] = run + b0;
    int* orow = ofs + (size_t)blk * (NCB + 1);       // row-major, coalesced
    if (t * 2     <= NCB) orow[t * 2]     = run;
    if (t * 2 + 1 <= NCB) orow[t * 2 + 1] = run + b0;
    __syncthreads();

    if (act) {
#pragma unroll
        for (int j = 0; j < 4; ++j) {
            int d = d4[j];
            stage[lcnt[d >> CBBITS] + myidx[j]] =
                ((unsigned)(d & (CB - 1)) << 17) | (unsigned)s4[j];
        }
    }
    __syncthreads();
    for (int i = t; i < nE; i += 512)
        pairs[(size_t)blk * TP + i] = stage[i];      // coalesced dump
}

// ---------------- bucket-local CSR build (782 x 512) --------------------
// Reads its ofs column DIRECTLY (o0/o1 share one 64B line per slice; 782
// independent L2-resident line-touches, latency-hidden — replaces k_tr).
// Then: slice-count scan -> direct sliceId map -> independent record
// fetch -> LDS scatter -> coalesced dump.
__global__ void __launch_bounds__(512) k_csr(
        const int* __restrict__ ofs, const unsigned* __restrict__ pairs,
        int* __restrict__ rbeg, int* __restrict__ rend, int* __restrict__ ssrc) {
    __shared__ unsigned stIn[WINB];      // 10.25 KB
    __shared__ int stOut[WINB];          // 10.25 KB
    __shared__ unsigned short sliceId[WINB];  // 5.12 KB
    __shared__ int o0s[NPB];             // slice start within its block seg
    __shared__ int cns[1026];            // slice-count scan (pad to 1024)
    __shared__ int lcnt[CB], lofs[CB], lcur[CB];
    __shared__ int wsum[2];
    __shared__ int wred[8];
    int B = blockIdx.x, t = threadIdx.x;
    int nvalid = min(CB, N_NODES - B * CB);
    int obase = B * WINB;

    // per-slice counts from the ofs column (strided but one line per slice)
    for (int s = t; s < NPB; s += 512) {
        const int* orow = ofs + (size_t)s * (NCB + 1) + B;
        int o0 = orow[0];
        int o1 = orow[1];
        o0s[s] = o0;
        cns[s] = o1 - o0;
    }
    for (int s = NPB + t; s < 1024; s += 512) cns[s] = 0;   // pad
    if (t < CB) {
        lcnt[t] = (t < nvalid) ? 1 : 0;   // self-loop pre-count
        lcur[t] = 1;                      // slot 0 = self-loop
    }
    __syncthreads();

    // exclusive scan over 1024 slice counts, 2/thread
    int a0 = cns[t * 2], a1 = cns[t * 2 + 1];
    int local = a0 + a1;
    int ln = t & 63, w = t >> 6;
    int sc2 = local;
#pragma unroll
    for (int off = 1; off < 64; off <<= 1) {
        int u = __shfl_up(sc2, off, 64);
        if (ln >= off) sc2 += u;
    }
    if (ln == 63) wred[w] = sc2;
    __syncthreads();
    if (t < 8) {
        int v = wred[t], s = v;
#pragma unroll
        for (int off = 1; off < 8; off <<= 1) {
            int u = __shfl_up(s, off, 8);
            if ((t & 7) >= off) s += u;
        }
        wred[t] = s - v;
    }
    __syncthreads();
    int run = wred[w] + sc2 - local;
    cns[t * 2] = run; cns[t * 2 + 1] = run + a0;   // exclusive bases
    __syncthreads();
    int m = cns[NPB];                    // total records (pads are zero)

    // direct slice map: owner writes its records' slice id (~2.8 each)
    for (int s = t; s < NPB; s += 512) {
        int j0 = cns[s], j1 = cns[s + 1];
        for (int j = j0; j < j1; ++j) sliceId[j] = (unsigned short)s;
    }
    __syncthreads();

    // record fetch: one LDS read for slice, independent global load
    for (int i = t; i < m; i += 512) {
        int s = sliceId[i];
        unsigned r = pairs[(size_t)s * TP + o0s[s] + (i - cns[s])];
        stIn[i] = r;
        atomicAdd(&lcnt[r >> 17], 1);
    }
    __syncthreads();

    // exclusive scan over 128 bins (first 2 waves carry data)
    int v = (t < CB) ? lcnt[t] : 0;
    int wv = t >> 6;
    int sc = v;
#pragma unroll
    for (int off = 1; off < 64; off <<= 1) {
        int u = __shfl_up(sc, off, 64);
        if (ln >= off) sc += u;
    }
    if (ln == 63 && wv < 2) wsum[wv] = sc;
    __syncthreads();
    int wbase = (wv == 1) ? wsum[0] : 0;
    int ex = wbase + sc - v;
    if (t < CB) {
        lofs[t] = ex;
        int gi = B * CB + t;
        if (gi < N_NODES) {
            rbeg[gi] = obase + ex;
            rend[gi] = obase + ex + v;
            stOut[ex] = gi;               // self-loop record, slot 0
        }
    }
    __syncthreads();

    // scatter into final CSR order (LDS -> LDS)
    for (int k = t; k < m; k += 512) {
        unsigned p = stIn[k];
        int dl = p >> 17;
        int idx = atomicAdd(&lcur[dl], 1);
        stOut[lofs[dl] + idx] = (int)(p & 0x1FFFF);
    }
    __syncthreads();

    // coalesced dump
    int tot = m + nvalid;
    for (int i = t; i < tot; i += 512) ssrc[obase + i] = stOut[i];
}

// ---------------- layer 1 gather + softmax + fused epilogue -------------
// 16 lanes per dst (4 dsts/wave), lane16 = (e = bit3 edge slot 0..1,
// h = lane&7 head). After the xor-8 reduce ALL 16 lanes hold the reduced
// sums, so the W1+ELU+W2 epilogue (old k_rec) runs unmasked in-wave
// (2x redundant across e — ~1 us total) and rec[d] is written directly:
// no 32 MB xsbuf round trip, one less dispatch.
__global__ void __launch_bounds__(256) k_gather1(
        const int* __restrict__ rbeg, const int* __restrict__ rend,
        const int* __restrict__ ssrc, const __half* __restrict__ nd,
        const float* __restrict__ ad1, const float* __restrict__ b1,
        const float* __restrict__ W1, const float* __restrict__ W2,
        const float* __restrict__ a_src2, const float* __restrict__ a_dst2,
        float4* __restrict__ rec) {
    int gtid = blockIdx.x * blockDim.x + threadIdx.x;
    int d      = gtid >> 4;
    int lane16 = threadIdx.x & 15;
    if (d >= N_NODES) return;
    int e = lane16 >> 3;       // edge slot (0..1)
    int h = lane16 & 7;        // head

    int beg = rbeg[d], end = rend[d];
    float adv = ad1[d * 8 + h];                // pre-scaled by log2e
    float c0 = 0.f, c1 = 0.f, c2 = 0.f, c3 = 0.f, c4 = 0.f, den = 0.f;

    for (int k = beg; k < end; k += 4) {       // 2 predicated 2-edge groups
        int kA = k + e, kB = k + 2 + e;
        bool vA = kA < end, vB = kB < end;
        int sA = ssrc[vA ? kA : beg];
        int sB = ssrc[vB ? kB : beg];
        float eA = __half2float(nd[(size_t)sA * 16 + h]);
        float eB = __half2float(nd[(size_t)sB * 16 + h]);
        float4 xA = *(const float4*)(nd + (size_t)sA * 16 + 8);  // same line as eA
        float4 xB = *(const float4*)(nd + (size_t)sB * 16 + 8);
        float tA = eA + adv; tA = fmaxf(tA, NEG_SLOPE * tA);
        float tB = eB + adv; tB = fmaxf(tB, NEG_SLOPE * tB);
        float wA = vA ? __builtin_amdgcn_exp2f(tA) : 0.f;
        float wB = vB ? __builtin_amdgcn_exp2f(tB) : 0.f;
        float2 A01 = __half22float2(*(__half2*)&xA.x);
        float2 A23 = __half22float2(*(__half2*)&xA.y);
        float2 A4_ = __half22float2(*(__half2*)&xA.z);
        float2 B01 = __half22float2(*(__half2*)&xB.x);
        float2 B23 = __half22float2(*(__half2*)&xB.y);
        float2 B4_ = __half22float2(*(__half2*)&xB.z);
        c0 += wA * A01.x + wB * B01.x;
        c1 += wA * A01.y + wB * B01.y;
        c2 += wA * A23.x + wB * B23.x;
        c3 += wA * A23.y + wB * B23.y;
        c4 += wA * A4_.x + wB * B4_.x;
        den += wA + wB;
    }

    // reduce across the 2 edge slots — afterwards all 16 lanes hold sums
#define REDH(x) x += __shfl_xor(x, 8, 64);
    REDH(c0) REDH(c1) REDH(c2) REDH(c3) REDH(c4) REDH(den)
#undef REDH

    // ---- fused epilogue (old k_rec), h = lane16 & 7, unmasked ----
    float inv = 1.f / den;                     // den>0 (self-loop guarantees)
    float xs[5] = { c0 * inv, c1 * inv, c2 * inv, c3 * inv, c4 * inv };

    float4 hA = ((const float4*)b1)[2 * h];
    float4 hB = ((const float4*)b1)[2 * h + 1];
#pragma unroll
    for (int c = 0; c < 5; ++c) {
        float xc = xs[c];
        float4 wA = *(const float4*)(W1 + c * 64 + 8 * h);
        float4 wB = *(const float4*)(W1 + c * 64 + 8 * h + 4);
        hA.x += xc * wA.x; hA.y += xc * wA.y; hA.z += xc * wA.z; hA.w += xc * wA.w;
        hB.x += xc * wB.x; hB.y += xc * wB.y; hB.z += xc * wB.z; hB.w += xc * wB.w;
    }
    float v0 = hA.x, v1 = hA.y, v2 = hA.z, v3 = hA.w;
    float v4 = hB.x, v5 = hB.y, v6 = hB.z, v7 = hB.w;
    v0 = (v0 > 0.f) ? v0 : (__expf(v0) - 1.f); // ELU
    v1 = (v1 > 0.f) ? v1 : (__expf(v1) - 1.f);
    v2 = (v2 > 0.f) ? v2 : (__expf(v2) - 1.f);
    v3 = (v3 > 0.f) ? v3 : (__expf(v3) - 1.f);
    v4 = (v4 > 0.f) ? v4 : (__expf(v4) - 1.f);
    v5 = (v5 > 0.f) ? v5 : (__expf(v5) - 1.f);
    v6 = (v6 > 0.f) ? v6 : (__expf(v6) - 1.f);
    v7 = (v7 > 0.f) ? v7 : (__expf(v7) - 1.f);

    const float4* w4 = (const float4*)(W2 + h * 16);
    float4 wq0 = w4[0], wq1 = w4[1], wq2 = w4[2], wq3 = w4[3];
    float h20 = v0 * wq0.x + v1 * wq0.z + v2 * wq1.x + v3 * wq1.z
              + v4 * wq2.x + v5 * wq2.z + v6 * wq3.x + v7 * wq3.z;
    float h21 = v0 * wq0.y + v1 * wq0.w + v2 * wq1.y + v3 * wq1.w
              + v4 * wq2.y + v5 * wq2.w + v6 * wq3.y + v7 * wq3.w;
    // reduce across the 8 heads (lane bits 0..2 — within each 16-group)
    h20 += __shfl_xor(h20, 1, 64); h20 += __shfl_xor(h20, 2, 64); h20 += __shfl_xor(h20, 4, 64);
    h21 += __shfl_xor(h21, 1, 64); h21 += __shfl_xor(h21, 2, 64); h21 += __shfl_xor(h21, 4, 64);

    if (lane16 == 0) {
        float as2v = (h20 * a_src2[0] + h21 * a_src2[1]) * LOG2E;
        float ad2v = (h20 * a_dst2[0] + h21 * a_dst2[1]) * LOG2E;
        rec[d] = make_float4(h20, h21, as2v, ad2v);
    }
}

// ---------------- layer 2: per-dst gather + log_softmax -----------------
// 8 lanes per dst (8 dsts/wave). rec.z/.w pre-scaled by log2e.
__global__ void __launch_bounds__(256) k_gather2(
        const int* __restrict__ rbeg, const int* __restrict__ rend,
        const int* __restrict__ ssrc, const float4* __restrict__ rec,
        const float* __restrict__ b2, float* __restrict__ out) {
    int gtid = blockIdx.x * blockDim.x + threadIdx.x;
    int d    = gtid >> 3;
    int lane = threadIdx.x & 7;
    if (d >= N_NODES) return;

    int beg = rbeg[d], end = rend[d];
    float adv = rec[d].w;
    float n0 = 0.f, n1 = 0.f, den = 0.f;
    for (int k = beg; k < end; k += 8) {
        int ki = k + lane;
        bool v = ki < end;
        int s = ssrc[v ? ki : beg];
        float4 r = rec[s];
        float t = r.z + adv; t = fmaxf(t, NEG_SLOPE * t);
        float w = v ? __builtin_amdgcn_exp2f(t) : 0.f;
        n0 += w * r.x; n1 += w * r.y; den += w;
    }
#pragma unroll
    for (int off = 1; off < 8; off <<= 1) {
        n0  += __shfl_xor(n0,  off, 8);
        n1  += __shfl_xor(n1,  off, 8);
        den += __shfl_xor(den, off, 8);
    }
    if (lane == 0) {
        float o0 = n0 / den + b2[0];
        float o1 = n1 / den + b2[1];
        float m  = fmaxf(o0, o1);
        float lse = m + __logf(__expf(o0 - m) + __expf(o1 - m));
        *(float2*)(out + (size_t)d * 2) = make_float2(o0 - lse, o1 - lse);
    }
}

extern "C" void kernel_launch(void* const* d_in, const int* in_sizes, int n_in,
                              void* d_out, int out_size, void* d_ws, size_t ws_size,
                              hipStream_t stream) {
    const float* x      = (const float*)d_in[0];
    const int*   ei     = (const int*)d_in[1];     // [2, E] int32
    const float* W1     = (const float*)d_in[2];
    const float* a_src1 = (const float*)d_in[3];
    const float* a_dst1 = (const float*)d_in[4];
    const float* b1     = (const float*)d_in[5];
    const float* W2     = (const float*)d_in[6];
    const float* a_src2 = (const float*)d_in[7];
    const float* a_dst2 = (const float*)d_in[8];
    const float* b2     = (const float*)d_in[9];
    float* out = (float*)d_out;

    const int* src = ei;
    const int* dst = ei + N_EDGES;

    // ---- workspace layout (~28 MB). ofs+pairs live only through k_csr.
    // Everything written before read.
    int* rbeg   = (int*)d_ws;                                   // N
    int* rend   = rbeg + N_NODES;                               // N
    int* ssrc   = rend + N_NODES;                               // NCB*WINB (8 MB)
    uintptr_t pp = ((uintptr_t)(ssrc + (size_t)NCB * WINB) + 255) & ~(uintptr_t)255;
    float4*   rec  = (float4*)pp;                               // N float4 (1.6 MB)
    float*    ad1  = (float*)(rec + N_NODES);                   // N*8 fp32 (3.2 MB)
    __half*   nd   = (__half*)(ad1 + (size_t)N_NODES * 8);      // N*16 fp16 (3.2 MB, packed as+x)
    uintptr_t rg = ((uintptr_t)(nd + (size_t)N_NODES * 16) + 255) & ~(uintptr_t)255;
    int*      ofs   = (int*)rg;                                 // NPB*(NCB+1) (2.45 MB)
    unsigned* pairs = (unsigned*)(ofs + (size_t)NPB * (NCB + 1)); // E (6.4 MB)

    k_np<<<NPB + NB_NODE1, 512, 0, stream>>>(src, dst, ofs, pairs,
                                             x, W1, a_src1, a_dst1,
                                             nd, ad1);
    k_csr<<<NCB, 512, 0, stream>>>(ofs, pairs, rbeg, rend, ssrc);
    k_gather1<<<(N_NODES * 16 + 255) / 256, 256, 0, stream>>>(rbeg, rend, ssrc,
                                                              nd, ad1, b1, W1, W2,
                                                              a_src2, a_dst2, rec);
    k_gather2<<<(N_NODES * 8 + 255) / 256, 256, 0, stream>>>(rbeg, rend, ssrc,
                                                             rec, b2, out);
}

// Round 15
// 151.868 us; speedup vs baseline: 1.1928x; 1.0051x over previous
//
#include <hip/hip_runtime.h>
#include <hip/hip_fp16.h>
#include <math.h>
#include <stdint.h>

#define N_NODES 100000
#define N_EDGES 1600000
#define NEG_SLOPE 0.2f
#define LOG2E 1.44269504088896340736f

#define CB     128                            // dst nodes per bucket
#define CBBITS 7
#define NCB    ((N_NODES + CB - 1) / CB)      // 782 buckets
#define TP     2048                           // edges per partition block
#define NPB    ((N_EDGES + TP - 1) / TP)      // 782 partition blocks
#define WINB   2560                           // fixed ssrc window per bucket (mean load 2174, +11 sigma)
#define NB_NODE1 ((N_NODES * 8 + 511) / 512)  // node1 blocks in fused kernel

typedef int nt_int4 __attribute__((ext_vector_type(4)));

// ---------------- fused: block-radix partition + node transform ---------
// Blocks [0, NPB): edge partition (LDS rank-sort, coalesced ofs rows +
// pairs dump). Blocks [NPB, ...): node transform writing the PACKED
// per-src record nd[n] = {as[0..7] fp16 (log2e-scaled) | x0..x4 fp16
// pad} — 32 B, so gather1's two per-edge loads share one 64B line.
__global__ void __launch_bounds__(512) k_np(
        const int* __restrict__ src, const int* __restrict__ dst,
        int* __restrict__ ofs, unsigned* __restrict__ pairs,
        const float* __restrict__ x, const float* __restrict__ W1,
        const float* __restrict__ a_src1, const float* __restrict__ a_dst1,
        __half* __restrict__ nd, float* __restrict__ ad1) {
    __shared__ int lcnt[1024];           // bins (782 used): counts -> bases
    __shared__ unsigned stage[TP];       // 8 KB
    __shared__ int wred[8];
    int t = threadIdx.x;

    if (blockIdx.x >= NPB) {
        // ---------- node1 half ----------
        int gid  = (blockIdx.x - NPB) * 512 + t;
        int n    = gid >> 3;
        int head = gid & 7;
        if (n >= N_NODES) return;

        float xv[5];
#pragma unroll
        for (int k = 0; k < 5; ++k) xv[k] = x[n * 5 + k];

        float as = 0.f, ad = 0.f;
#pragma unroll
        for (int j = 0; j < 8; ++j) {
            int c = head * 8 + j;
            float acc = 0.f;
#pragma unroll
            for (int k = 0; k < 5; ++k) acc += xv[k] * W1[k * 64 + c];
            as += acc * a_src1[c];
            ad += acc * a_dst1[c];
        }
        nd[(size_t)n * 16 + head] = __float2half(as * LOG2E);   // 8 consecutive halves
        ad1[n * 8 + head] = ad * LOG2E;

        if (head == 0) {                // x chunk: halves 8..15 of the record
            __half2 p0 = __halves2half2(__float2half(xv[0]), __float2half(xv[1]));
            __half2 p1 = __halves2half2(__float2half(xv[2]), __float2half(xv[3]));
            __half2 p2 = __halves2half2(__float2half(xv[4]), __float2half(0.f));
            __half2 p3 = __halves2half2(__float2half(0.f), __float2half(0.f));
            __half2* xp = (__half2*)&nd[(size_t)n * 16 + 8];    // byte ofs n*32+16, 16B-aligned
            xp[0] = p0; xp[1] = p1; xp[2] = p2; xp[3] = p3;
        }
        return;
    }

    // ---------- partition half ----------
    int blk = blockIdx.x;
    int base = blk * TP + t * 4;
    bool act = base < N_EDGES;           // tail block: exact multiple of 4
    int nE = min(TP, N_EDGES - blk * TP);

    lcnt[t] = 0; lcnt[t + 512] = 0;
    __syncthreads();

    nt_int4 s4, d4;
    int myidx[4];
    if (act) {
        s4 = __builtin_nontemporal_load((const nt_int4*)(src + base));
        d4 = __builtin_nontemporal_load((const nt_int4*)(dst + base));
#pragma unroll
        for (int j = 0; j < 4; ++j)
            myidx[j] = atomicAdd(&lcnt[d4[j] >> CBBITS], 1);
    }
    __syncthreads();

    // exclusive scan over 1024 bins, 2/thread: wave-shuffle scan
    int b0 = lcnt[t * 2], b1 = lcnt[t * 2 + 1];
    int local = b0 + b1;
    int ln = t & 63, w = t >> 6;
    int sc = local;
#pragma unroll
    for (int off = 1; off < 64; off <<= 1) {
        int u = __shfl_up(sc, off, 64);
        if (ln >= off) sc += u;
    }
    if (ln == 63) wred[w] = sc;          // per-wave total
    __syncthreads();
    if (t < 8) {                         // scan the 8 wave totals
        int v = wred[t], s = v;
#pragma unroll
        for (int off = 1; off < 8; off <<= 1) {
            int u = __shfl_up(s, off, 8);
            if ((t & 7) >= off) s += u;
        }
        wred[t] = s - v;                 // exclusive base per wave
    }
    __syncthreads();
    int run = wred[w] + sc - local;      // exclusive prefix of this thread's 2 bins
    lcnt[t * 2] = run; lcnt[t * 2 + 1] = run + b0;
    int* orow = ofs + (size_t)blk * (NCB + 1);       // row-major, coalesced
    if (t * 2     <= NCB) orow[t * 2]     = run;
    if (t * 2 + 1 <= NCB) orow[t * 2 + 1] = run + b0;
    __syncthreads();

    if (act) {
#pragma unroll
        for (int j = 0; j < 4; ++j) {
            int d = d4[j];
            stage[lcnt[d >> CBBITS] + myidx[j]] =
                ((unsigned)(d & (CB - 1)) << 17) | (unsigned)s4[j];
        }
    }
    __syncthreads();
    for (int i = t; i < nE; i += 512)
        pairs[(size_t)blk * TP + i] = stage[i];      // coalesced dump
}

// ---------------- bucket-local CSR build (782 x 512) --------------------
// Reads its ofs column DIRECTLY (o0/o1 share one 64B line per slice).
// Then: slice-count scan -> direct sliceId map -> independent record
// fetch -> LDS scatter -> coalesced dump.
__global__ void __launch_bounds__(512) k_csr(
        const int* __restrict__ ofs, const unsigned* __restrict__ pairs,
        int* __restrict__ rbeg, int* __restrict__ rend, int* __restrict__ ssrc) {
    __shared__ unsigned stIn[WINB];      // 10.25 KB
    __shared__ int stOut[WINB];          // 10.25 KB
    __shared__ unsigned short sliceId[WINB];  // 5.12 KB
    __shared__ int o0s[NPB];             // slice start within its block seg
    __shared__ int cns[1026];            // slice-count scan (pad to 1024)
    __shared__ int lcnt[CB], lofs[CB], lcur[CB];
    __shared__ int wsum[2];
    __shared__ int wred[8];
    int B = blockIdx.x, t = threadIdx.x;
    int nvalid = min(CB, N_NODES - B * CB);
    int obase = B * WINB;

    // per-slice counts from the ofs column (strided but one line per slice)
    for (int s = t; s < NPB; s += 512) {
        const int* orow = ofs + (size_t)s * (NCB + 1) + B;
        int o0 = orow[0];
        int o1 = orow[1];
        o0s[s] = o0;
        cns[s] = o1 - o0;
    }
    for (int s = NPB + t; s < 1024; s += 512) cns[s] = 0;   // pad
    if (t < CB) {
        lcnt[t] = (t < nvalid) ? 1 : 0;   // self-loop pre-count
        lcur[t] = 1;                      // slot 0 = self-loop
    }
    __syncthreads();

    // exclusive scan over 1024 slice counts, 2/thread
    int a0 = cns[t * 2], a1 = cns[t * 2 + 1];
    int local = a0 + a1;
    int ln = t & 63, w = t >> 6;
    int sc2 = local;
#pragma unroll
    for (int off = 1; off < 64; off <<= 1) {
        int u = __shfl_up(sc2, off, 64);
        if (ln >= off) sc2 += u;
    }
    if (ln == 63) wred[w] = sc2;
    __syncthreads();
    if (t < 8) {
        int v = wred[t], s = v;
#pragma unroll
        for (int off = 1; off < 8; off <<= 1) {
            int u = __shfl_up(s, off, 8);
            if ((t & 7) >= off) s += u;
        }
        wred[t] = s - v;
    }
    __syncthreads();
    int run = wred[w] + sc2 - local;
    cns[t * 2] = run; cns[t * 2 + 1] = run + a0;   // exclusive bases
    __syncthreads();
    int m = cns[NPB];                    // total records (pads are zero)

    // direct slice map: owner writes its records' slice id (~2.8 each)
    for (int s = t; s < NPB; s += 512) {
        int j0 = cns[s], j1 = cns[s + 1];
        for (int j = j0; j < j1; ++j) sliceId[j] = (unsigned short)s;
    }
    __syncthreads();

    // record fetch: one LDS read for slice, independent global load
    for (int i = t; i < m; i += 512) {
        int s = sliceId[i];
        unsigned r = pairs[(size_t)s * TP + o0s[s] + (i - cns[s])];
        stIn[i] = r;
        atomicAdd(&lcnt[r >> 17], 1);
    }
    __syncthreads();

    // exclusive scan over 128 bins (first 2 waves carry data)
    int v = (t < CB) ? lcnt[t] : 0;
    int wv = t >> 6;
    int sc = v;
#pragma unroll
    for (int off = 1; off < 64; off <<= 1) {
        int u = __shfl_up(sc, off, 64);
        if (ln >= off) sc += u;
    }
    if (ln == 63 && wv < 2) wsum[wv] = sc;
    __syncthreads();
    int wbase = (wv == 1) ? wsum[0] : 0;
    int ex = wbase + sc - v;
    if (t < CB) {
        lofs[t] = ex;
        int gi = B * CB + t;
        if (gi < N_NODES) {
            rbeg[gi] = obase + ex;
            rend[gi] = obase + ex + v;
            stOut[ex] = gi;               // self-loop record, slot 0
        }
    }
    __syncthreads();

    // scatter into final CSR order (LDS -> LDS)
    for (int k = t; k < m; k += 512) {
        unsigned p = stIn[k];
        int dl = p >> 17;
        int idx = atomicAdd(&lcur[dl], 1);
        stOut[lofs[dl] + idx] = (int)(p & 0x1FFFF);
    }
    __syncthreads();

    // coalesced dump
    int tot = m + nvalid;
    for (int i = t; i < tot; i += 512) ssrc[obase + i] = stOut[i];
}

// ---------------- layer 1 gather + softmax + fused epilogue -------------
// 16 lanes per dst (4 dsts/wave), lane16 = (e = bit3 edge slot 0..1,
// h = lane&7 head). x2-unrolled loop: 4 predicated 2-edge groups = 8
// edges / 12 loads in flight per dst per iteration (ILP for L2/L3
// latency). Epilogue (W1+ELU+W2) runs unmasked in-wave; rec[d] written
// directly.
__global__ void __launch_bounds__(256) k_gather1(
        const int* __restrict__ rbeg, const int* __restrict__ rend,
        const int* __restrict__ ssrc, const __half* __restrict__ nd,
        const float* __restrict__ ad1, const float* __restrict__ b1,
        const float* __restrict__ W1, const float* __restrict__ W2,
        const float* __restrict__ a_src2, const float* __restrict__ a_dst2,
        float4* __restrict__ rec) {
    int gtid = blockIdx.x * blockDim.x + threadIdx.x;
    int d      = gtid >> 4;
    int lane16 = threadIdx.x & 15;
    if (d >= N_NODES) return;
    int e = lane16 >> 3;       // edge slot (0..1)
    int h = lane16 & 7;        // head

    int beg = rbeg[d], end = rend[d];
    float adv = ad1[d * 8 + h];                // pre-scaled by log2e
    float c0 = 0.f, c1 = 0.f, c2 = 0.f, c3 = 0.f, c4 = 0.f, den = 0.f;

    for (int k = beg; k < end; k += 8) {       // 4 predicated 2-edge groups
        int kA = k + e, kB = k + 2 + e, kC = k + 4 + e, kD = k + 6 + e;
        bool vA = kA < end, vB = kB < end, vC = kC < end, vD = kD < end;
        int sA = ssrc[vA ? kA : beg];
        int sB = ssrc[vB ? kB : beg];
        int sC = ssrc[vC ? kC : beg];
        int sD = ssrc[vD ? kD : beg];
        float eA = __half2float(nd[(size_t)sA * 16 + h]);
        float eB = __half2float(nd[(size_t)sB * 16 + h]);
        float eC = __half2float(nd[(size_t)sC * 16 + h]);
        float eD = __half2float(nd[(size_t)sD * 16 + h]);
        float4 xA = *(const float4*)(nd + (size_t)sA * 16 + 8);  // same line as eA
        float4 xB = *(const float4*)(nd + (size_t)sB * 16 + 8);
        float4 xC = *(const float4*)(nd + (size_t)sC * 16 + 8);
        float4 xD = *(const float4*)(nd + (size_t)sD * 16 + 8);
        float tA = eA + adv; tA = fmaxf(tA, NEG_SLOPE * tA);
        float tB = eB + adv; tB = fmaxf(tB, NEG_SLOPE * tB);
        float tC = eC + adv; tC = fmaxf(tC, NEG_SLOPE * tC);
        float tD = eD + adv; tD = fmaxf(tD, NEG_SLOPE * tD);
        float wA = vA ? __builtin_amdgcn_exp2f(tA) : 0.f;
        float wB = vB ? __builtin_amdgcn_exp2f(tB) : 0.f;
        float wC = vC ? __builtin_amdgcn_exp2f(tC) : 0.f;
        float wD = vD ? __builtin_amdgcn_exp2f(tD) : 0.f;
        float2 A01 = __half22float2(*(__half2*)&xA.x);
        float2 A23 = __half22float2(*(__half2*)&xA.y);
        float2 A4_ = __half22float2(*(__half2*)&xA.z);
        float2 B01 = __half22float2(*(__half2*)&xB.x);
        float2 B23 = __half22float2(*(__half2*)&xB.y);
        float2 B4_ = __half22float2(*(__half2*)&xB.z);
        float2 C01 = __half22float2(*(__half2*)&xC.x);
        float2 C23 = __half22float2(*(__half2*)&xC.y);
        float2 C4_ = __half22float2(*(__half2*)&xC.z);
        float2 D01 = __half22float2(*(__half2*)&xD.x);
        float2 D23 = __half22float2(*(__half2*)&xD.y);
        float2 D4_ = __half22float2(*(__half2*)&xD.z);
        c0 += wA * A01.x + wB * B01.x + wC * C01.x + wD * D01.x;
        c1 += wA * A01.y + wB * B01.y + wC * C01.y + wD * D01.y;
        c2 += wA * A23.x + wB * B23.x + wC * C23.x + wD * D23.x;
        c3 += wA * A23.y + wB * B23.y + wC * C23.y + wD * D23.y;
        c4 += wA * A4_.x + wB * B4_.x + wC * C4_.x + wD * D4_.x;
        den += wA + wB + wC + wD;
    }

    // reduce across the 2 edge slots — afterwards all 16 lanes hold sums
#define REDH(x) x += __shfl_xor(x, 8, 64);
    REDH(c0) REDH(c1) REDH(c2) REDH(c3) REDH(c4) REDH(den)
#undef REDH

    // ---- fused epilogue (old k_rec), h = lane16 & 7, unmasked ----
    float inv = 1.f / den;                     // den>0 (self-loop guarantees)
    float xs[5] = { c0 * inv, c1 * inv, c2 * inv, c3 * inv, c4 * inv };

    float4 hA = ((const float4*)b1)[2 * h];
    float4 hB = ((const float4*)b1)[2 * h + 1];
#pragma unroll
    for (int c = 0; c < 5; ++c) {
        float xc = xs[c];
        float4 wA = *(const float4*)(W1 + c * 64 + 8 * h);
        float4 wB = *(const float4*)(W1 + c * 64 + 8 * h + 4);
        hA.x += xc * wA.x; hA.y += xc * wA.y; hA.z += xc * wA.z; hA.w += xc * wA.w;
        hB.x += xc * wB.x; hB.y += xc * wB.y; hB.z += xc * wB.z; hB.w += xc * wB.w;
    }
    float v0 = hA.x, v1 = hA.y, v2 = hA.z, v3 = hA.w;
    float v4 = hB.x, v5 = hB.y, v6 = hB.z, v7 = hB.w;
    v0 = (v0 > 0.f) ? v0 : (__expf(v0) - 1.f); // ELU
    v1 = (v1 > 0.f) ? v1 : (__expf(v1) - 1.f);
    v2 = (v2 > 0.f) ? v2 : (__expf(v2) - 1.f);
    v3 = (v3 > 0.f) ? v3 : (__expf(v3) - 1.f);
    v4 = (v4 > 0.f) ? v4 : (__expf(v4) - 1.f);
    v5 = (v5 > 0.f) ? v5 : (__expf(v5) - 1.f);
    v6 = (v6 > 0.f) ? v6 : (__expf(v6) - 1.f);
    v7 = (v7 > 0.f) ? v7 : (__expf(v7) - 1.f);

    const float4* w4 = (const float4*)(W2 + h * 16);
    float4 wq0 = w4[0], wq1 = w4[1], wq2 = w4[2], wq3 = w4[3];
    float h20 = v0 * wq0.x + v1 * wq0.z + v2 * wq1.x + v3 * wq1.z
              + v4 * wq2.x + v5 * wq2.z + v6 * wq3.x + v7 * wq3.z;
    float h21 = v0 * wq0.y + v1 * wq0.w + v2 * wq1.y + v3 * wq1.w
              + v4 * wq2.y + v5 * wq2.w + v6 * wq3.y + v7 * wq3.w;
    // reduce across the 8 heads (lane bits 0..2 — within each 16-group)
    h20 += __shfl_xor(h20, 1, 64); h20 += __shfl_xor(h20, 2, 64); h20 += __shfl_xor(h20, 4, 64);
    h21 += __shfl_xor(h21, 1, 64); h21 += __shfl_xor(h21, 2, 64); h21 += __shfl_xor(h21, 4, 64);

    if (lane16 == 0) {
        float as2v = (h20 * a_src2[0] + h21 * a_src2[1]) * LOG2E;
        float ad2v = (h20 * a_dst2[0] + h21 * a_dst2[1]) * LOG2E;
        rec[d] = make_float4(h20, h21, as2v, ad2v);
    }
}

// ---------------- layer 2: per-dst gather + log_softmax -----------------
// 8 lanes per dst (8 dsts/wave). rec.z/.w pre-scaled by log2e.
// x2-unrolled: 2 predicated 8-edge groups = 16 edges in flight.
__global__ void __launch_bounds__(256) k_gather2(
        const int* __restrict__ rbeg, const int* __restrict__ rend,
        const int* __restrict__ ssrc, const float4* __restrict__ rec,
        const float* __restrict__ b2, float* __restrict__ out) {
    int gtid = blockIdx.x * blockDim.x + threadIdx.x;
    int d    = gtid >> 3;
    int lane = threadIdx.x & 7;
    if (d >= N_NODES) return;

    int beg = rbeg[d], end = rend[d];
    float adv = rec[d].w;
    float n0 = 0.f, n1 = 0.f, den = 0.f;
    for (int k = beg; k < end; k += 16) {
        int kA = k + lane, kB = k + 8 + lane;
        bool vA = kA < end, vB = kB < end;
        int sA = ssrc[vA ? kA : beg];
        int sB = ssrc[vB ? kB : beg];
        float4 rA = rec[sA];
        float4 rB = rec[sB];
        float tA = rA.z + adv; tA = fmaxf(tA, NEG_SLOPE * tA);
        float tB = rB.z + adv; tB = fmaxf(tB, NEG_SLOPE * tB);
        float wA = vA ? __builtin_amdgcn_exp2f(tA) : 0.f;
        float wB = vB ? __builtin_amdgcn_exp2f(tB) : 0.f;
        n0 += wA * rA.x + wB * rB.x;
        n1 += wA * rA.y + wB * rB.y;
        den += wA + wB;
    }
#pragma unroll
    for (int off = 1; off < 8; off <<= 1) {
        n0  += __shfl_xor(n0,  off, 8);
        n1  += __shfl_xor(n1,  off, 8);
        den += __shfl_xor(den, off, 8);
    }
    if (lane == 0) {
        float o0 = n0 / den + b2[0];
        float o1 = n1 / den + b2[1];
        float m  = fmaxf(o0, o1);
        float lse = m + __logf(__expf(o0 - m) + __expf(o1 - m));
        *(float2*)(out + (size_t)d * 2) = make_float2(o0 - lse, o1 - lse);
    }
}

extern "C" void kernel_launch(void* const* d_in, const int* in_sizes, int n_in,
                              void* d_out, int out_size, void* d_ws, size_t ws_size,
                              hipStream_t stream) {
    const float* x      = (const float*)d_in[0];
    const int*   ei     = (const int*)d_in[1];     // [2, E] int32
    const float* W1     = (const float*)d_in[2];
    const float* a_src1 = (const float*)d_in[3];
    const float* a_dst1 = (const float*)d_in[4];
    const float* b1     = (const float*)d_in[5];
    const float* W2     = (const float*)d_in[6];
    const float* a_src2 = (const float*)d_in[7];
    const float* a_dst2 = (const float*)d_in[8];
    const float* b2     = (const float*)d_in[9];
    float* out = (float*)d_out;

    const int* src = ei;
    const int* dst = ei + N_EDGES;

    // ---- workspace layout (~28 MB). ofs+pairs live only through k_csr.
    // Everything written before read.
    int* rbeg   = (int*)d_ws;                                   // N
    int* rend   = rbeg + N_NODES;                               // N
    int* ssrc   = rend + N_NODES;                               // NCB*WINB (8 MB)
    uintptr_t pp = ((uintptr_t)(ssrc + (size_t)NCB * WINB) + 255) & ~(uintptr_t)255;
    float4*   rec  = (float4*)pp;                               // N float4 (1.6 MB)
    float*    ad1  = (float*)(rec + N_NODES);                   // N*8 fp32 (3.2 MB)
    __half*   nd   = (__half*)(ad1 + (size_t)N_NODES * 8);      // N*16 fp16 (3.2 MB, packed as+x)
    uintptr_t rg = ((uintptr_t)(nd + (size_t)N_NODES * 16) + 255) & ~(uintptr_t)255;
    int*      ofs   = (int*)rg;                                 // NPB*(NCB+1) (2.45 MB)
    unsigned* pairs = (unsigned*)(ofs + (size_t)NPB * (NCB + 1)); // E (6.4 MB)

    k_np<<<NPB + NB_NODE1, 512, 0, stream>>>(src, dst, ofs, pairs,
                                             x, W1, a_src1, a_dst1,
                                             nd, ad1);
    k_csr<<<NCB, 512, 0, stream>>>(ofs, pairs, rbeg, rend, ssrc);
    k_gather1<<<(N_NODES * 16 + 255) / 256, 256, 0, stream>>>(rbeg, rend, ssrc,
                                                              nd, ad1, b1, W1, W2,
                                                              a_src2, a_dst2, rec);
    k_gather2<<<(N_NODES * 8 + 255) / 256, 256, 0, stream>>>(rbeg, rend, ssrc,
                                                             rec, b2, out);
}

// Round 17
// 149.724 us; speedup vs baseline: 1.2099x; 1.0143x over previous
//
#include <hip/hip_runtime.h>
#include <hip/hip_fp16.h>
#include <math.h>
#include <stdint.h>

#define N_NODES 100000
#define N_EDGES 1600000
#define NEG_SLOPE 0.2f
#define LOG2E 1.44269504088896340736f

#define CB     128                            // dst nodes per bucket
#define CBBITS 7
#define NCB    ((N_NODES + CB - 1) / CB)      // 782 buckets
#define TP     2048                           // edges per partition block
#define NPB    ((N_EDGES + TP - 1) / TP)      // 782 partition blocks
#define WINB   2560                           // fixed ssrc window per bucket (mean load 2174, +11 sigma)
#define NB_NODE1 ((N_NODES * 8 + 511) / 512)  // node1 blocks in fused kernel

typedef int nt_int4 __attribute__((ext_vector_type(4)));

// ---------------- fused: block-radix partition + node transform ---------
// Blocks [0, NPB): edge partition (LDS rank-sort, coalesced ofs rows +
// pairs dump). Blocks [NPB, ...): node transform writing the PACKED
// per-src record nd[n] = {as[0..7] fp16 (log2e-scaled) | x0..x4 fp16
// pad} — 32 B, so gather1's two per-edge loads share one 64B line.
__global__ void __launch_bounds__(512) k_np(
        const int* __restrict__ src, const int* __restrict__ dst,
        int* __restrict__ ofs, unsigned* __restrict__ pairs,
        const float* __restrict__ x, const float* __restrict__ W1,
        const float* __restrict__ a_src1, const float* __restrict__ a_dst1,
        __half* __restrict__ nd, float* __restrict__ ad1) {
    __shared__ int lcnt[1024];           // bins (782 used): counts -> bases
    __shared__ unsigned stage[TP];       // 8 KB
    __shared__ int wred[8];
    int t = threadIdx.x;

    if (blockIdx.x >= NPB) {
        // ---------- node1 half ----------
        int gid  = (blockIdx.x - NPB) * 512 + t;
        int n    = gid >> 3;
        int head = gid & 7;
        if (n >= N_NODES) return;

        float xv[5];
#pragma unroll
        for (int k = 0; k < 5; ++k) xv[k] = x[n * 5 + k];

        float as = 0.f, ad = 0.f;
#pragma unroll
        for (int j = 0; j < 8; ++j) {
            int c = head * 8 + j;
            float acc = 0.f;
#pragma unroll
            for (int k = 0; k < 5; ++k) acc += xv[k] * W1[k * 64 + c];
            as += acc * a_src1[c];
            ad += acc * a_dst1[c];
        }
        nd[(size_t)n * 16 + head] = __float2half(as * LOG2E);   // 8 consecutive halves
        ad1[n * 8 + head] = ad * LOG2E;

        if (head == 0) {                // x chunk: halves 8..15 of the record
            __half2 p0 = __halves2half2(__float2half(xv[0]), __float2half(xv[1]));
            __half2 p1 = __halves2half2(__float2half(xv[2]), __float2half(xv[3]));
            __half2 p2 = __halves2half2(__float2half(xv[4]), __float2half(0.f));
            __half2 p3 = __halves2half2(__float2half(0.f), __float2half(0.f));
            __half2* xp = (__half2*)&nd[(size_t)n * 16 + 8];    // byte ofs n*32+16, 16B-aligned
            xp[0] = p0; xp[1] = p1; xp[2] = p2; xp[3] = p3;
        }
        return;
    }

    // ---------- partition half ----------
    int blk = blockIdx.x;
    int base = blk * TP + t * 4;
    bool act = base < N_EDGES;           // tail block: exact multiple of 4
    int nE = min(TP, N_EDGES - blk * TP);

    lcnt[t] = 0; lcnt[t + 512] = 0;
    __syncthreads();

    nt_int4 s4, d4;
    int myidx[4];
    if (act) {
        s4 = __builtin_nontemporal_load((const nt_int4*)(src + base));
        d4 = __builtin_nontemporal_load((const nt_int4*)(dst + base));
#pragma unroll
        for (int j = 0; j < 4; ++j)
            myidx[j] = atomicAdd(&lcnt[d4[j] >> CBBITS], 1);
    }
    __syncthreads();

    // exclusive scan over 1024 bins, 2/thread: wave-shuffle scan
    int b0 = lcnt[t * 2], b1 = lcnt[t * 2 + 1];
    int local = b0 + b1;
    int ln = t & 63, w = t >> 6;
    int sc = local;
#pragma unroll
    for (int off = 1; off < 64; off <<= 1) {
        int u = __shfl_up(sc, off, 64);
        if (ln >= off) sc += u;
    }
    if (ln == 63) wred[w] = sc;          // per-wave total
    __syncthreads();
    if (t < 8) {                         // scan the 8 wave totals
        int v = wred[t], s = v;
#pragma unroll
        for (int off = 1; off < 8; off <<= 1) {
            int u = __shfl_up(s, off, 8);
            if ((t & 7) >= off) s += u;
        }
        wred[t] = s - v;                 // exclusive base per wave
    }
    __syncthreads();
    int run = wred[w] + sc - local;      // exclusive prefix of this thread's 2 bins
    lcnt[t * 2] = run; lcnt[t * 2 + 1] = run + b0;
    int* orow = ofs + (size_t)blk * (NCB + 1);       // row-major, coalesced
    if (t * 2     <= NCB) orow[t * 2]     = run;
    if (t * 2 + 1 <= NCB) orow[t * 2 + 1] = run + b0;
    __syncthreads();

    if (act) {
#pragma unroll
        for (int j = 0; j < 4; ++j) {
            int d = d4[j];
            stage[lcnt[d >> CBBITS] + myidx[j]] =
                ((unsigned)(d & (CB - 1)) << 17) | (unsigned)s4[j];
        }
    }
    __syncthreads();
    for (int i = t; i < nE; i += 512)
        pairs[(size_t)blk * TP + i] = stage[i];      // coalesced dump
}

// ---------------- bucket-local CSR build (782 x 512) --------------------
// Reads its ofs column DIRECTLY (o0/o1 share one 64B line per slice).
// Then: slice-count scan -> direct sliceId map -> independent record
// fetch -> LDS scatter -> coalesced dump.
__global__ void __launch_bounds__(512) k_csr(
        const int* __restrict__ ofs, const unsigned* __restrict__ pairs,
        int* __restrict__ rbeg, int* __restrict__ rend, int* __restrict__ ssrc) {
    __shared__ unsigned stIn[WINB];      // 10.25 KB
    __shared__ int stOut[WINB];          // 10.25 KB
    __shared__ unsigned short sliceId[WINB];  // 5.12 KB
    __shared__ int o0s[NPB];             // slice start within its block seg
    __shared__ int cns[1026];            // slice-count scan (pad to 1024)
    __shared__ int lcnt[CB], lofs[CB], lcur[CB];
    __shared__ int wsum[2];
    __shared__ int wred[8];
    int B = blockIdx.x, t = threadIdx.x;
    int nvalid = min(CB, N_NODES - B * CB);
    int obase = B * WINB;

    // per-slice counts from the ofs column (strided but one line per slice)
    for (int s = t; s < NPB; s += 512) {
        const int* orow = ofs + (size_t)s * (NCB + 1) + B;
        int o0 = orow[0];
        int o1 = orow[1];
        o0s[s] = o0;
        cns[s] = o1 - o0;
    }
    for (int s = NPB + t; s < 1024; s += 512) cns[s] = 0;   // pad
    if (t < CB) {
        lcnt[t] = (t < nvalid) ? 1 : 0;   // self-loop pre-count
        lcur[t] = 1;                      // slot 0 = self-loop
    }
    __syncthreads();

    // exclusive scan over 1024 slice counts, 2/thread
    int a0 = cns[t * 2], a1 = cns[t * 2 + 1];
    int local = a0 + a1;
    int ln = t & 63, w = t >> 6;
    int sc2 = local;
#pragma unroll
    for (int off = 1; off < 64; off <<= 1) {
        int u = __shfl_up(sc2, off, 64);
        if (ln >= off) sc2 += u;
    }
    if (ln == 63) wred[w] = sc2;
    __syncthreads();
    if (t < 8) {
        int v = wred[t], s = v;
#pragma unroll
        for (int off = 1; off < 8; off <<= 1) {
            int u = __shfl_up(s, off, 8);
            if ((t & 7) >= off) s += u;
        }
        wred[t] = s - v;
    }
    __syncthreads();
    int run = wred[w] + sc2 - local;
    cns[t * 2] = run; cns[t * 2 + 1] = run + a0;   // exclusive bases
    __syncthreads();
    int m = cns[NPB];                    // total records (pads are zero)

    // direct slice map: owner writes its records' slice id (~2.8 each)
    for (int s = t; s < NPB; s += 512) {
        int j0 = cns[s], j1 = cns[s + 1];
        for (int j = j0; j < j1; ++j) sliceId[j] = (unsigned short)s;
    }
    __syncthreads();

    // record fetch: one LDS read for slice, independent global load
    for (int i = t; i < m; i += 512) {
        int s = sliceId[i];
        unsigned r = pairs[(size_t)s * TP + o0s[s] + (i - cns[s])];
        stIn[i] = r;
        atomicAdd(&lcnt[r >> 17], 1);
    }
    __syncthreads();

    // exclusive scan over 128 bins (first 2 waves carry data)
    int v = (t < CB) ? lcnt[t] : 0;
    int wv = t >> 6;
    int sc = v;
#pragma unroll
    for (int off = 1; off < 64; off <<= 1) {
        int u = __shfl_up(sc, off, 64);
        if (ln >= off) sc += u;
    }
    if (ln == 63 && wv < 2) wsum[wv] = sc;
    __syncthreads();
    int wbase = (wv == 1) ? wsum[0] : 0;
    int ex = wbase + sc - v;
    if (t < CB) {
        lofs[t] = ex;
        int gi = B * CB + t;
        if (gi < N_NODES) {
            rbeg[gi] = obase + ex;
            rend[gi] = obase + ex + v;
            stOut[ex] = gi;               // self-loop record, slot 0
        }
    }
    __syncthreads();

    // scatter into final CSR order (LDS -> LDS)
    for (int k = t; k < m; k += 512) {
        unsigned p = stIn[k];
        int dl = p >> 17;
        int idx = atomicAdd(&lcur[dl], 1);
        stOut[lofs[dl] + idx] = (int)(p & 0x1FFFF);
    }
    __syncthreads();

    // coalesced dump
    int tot = m + nvalid;
    for (int i = t; i < tot; i += 512) ssrc[obase + i] = stOut[i];
}

// ---------------- layer 1 gather + softmax + fused epilogue -------------
// 16 lanes per dst (4 dsts/wave), lane16 = (e = bit3 edge slot 0..1,
// h = lane&7 head). x2-unrolled loop: 4 predicated 2-edge groups = 8
// edges / 12 loads in flight per dst per iteration (ILP for L2/L3
// latency). Epilogue (W1+ELU+W2) runs unmasked in-wave; rec[d] written
// directly.
__global__ void __launch_bounds__(256) k_gather1(
        const int* __restrict__ rbeg, const int* __restrict__ rend,
        const int* __restrict__ ssrc, const __half* __restrict__ nd,
        const float* __restrict__ ad1, const float* __restrict__ b1,
        const float* __restrict__ W1, const float* __restrict__ W2,
        const float* __restrict__ a_src2, const float* __restrict__ a_dst2,
        float4* __restrict__ rec) {
    int gtid = blockIdx.x * blockDim.x + threadIdx.x;
    int d      = gtid >> 4;
    int lane16 = threadIdx.x & 15;
    if (d >= N_NODES) return;
    int e = lane16 >> 3;       // edge slot (0..1)
    int h = lane16 & 7;        // head

    int beg = rbeg[d], end = rend[d];
    float adv = ad1[d * 8 + h];                // pre-scaled by log2e
    float c0 = 0.f, c1 = 0.f, c2 = 0.f, c3 = 0.f, c4 = 0.f, den = 0.f;

    for (int k = beg; k < end; k += 8) {       // 4 predicated 2-edge groups
        int kA = k + e, kB = k + 2 + e, kC = k + 4 + e, kD = k + 6 + e;
        bool vA = kA < end, vB = kB < end, vC = kC < end, vD = kD < end;
        int sA = ssrc[vA ? kA : beg];
        int sB = ssrc[vB ? kB : beg];
        int sC = ssrc[vC ? kC : beg];
        int sD = ssrc[vD ? kD : beg];
        float eA = __half2float(nd[(size_t)sA * 16 + h]);
        float eB = __half2float(nd[(size_t)sB * 16 + h]);
        float eC = __half2float(nd[(size_t)sC * 16 + h]);
        float eD = __half2float(nd[(size_t)sD * 16 + h]);
        float4 xA = *(const float4*)(nd + (size_t)sA * 16 + 8);  // same line as eA
        float4 xB = *(const float4*)(nd + (size_t)sB * 16 + 8);
        float4 xC = *(const float4*)(nd + (size_t)sC * 16 + 8);
        float4 xD = *(const float4*)(nd + (size_t)sD * 16 + 8);
        float tA = eA + adv; tA = fmaxf(tA, NEG_SLOPE * tA);
        float tB = eB + adv; tB = fmaxf(tB, NEG_SLOPE * tB);
        float tC = eC + adv; tC = fmaxf(tC, NEG_SLOPE * tC);
        float tD = eD + adv; tD = fmaxf(tD, NEG_SLOPE * tD);
        float wA = vA ? __builtin_amdgcn_exp2f(tA) : 0.f;
        float wB = vB ? __builtin_amdgcn_exp2f(tB) : 0.f;
        float wC = vC ? __builtin_amdgcn_exp2f(tC) : 0.f;
        float wD = vD ? __builtin_amdgcn_exp2f(tD) : 0.f;
        float2 A01 = __half22float2(*(__half2*)&xA.x);
        float2 A23 = __half22float2(*(__half2*)&xA.y);
        float2 A4_ = __half22float2(*(__half2*)&xA.z);
        float2 B01 = __half22float2(*(__half2*)&xB.x);
        float2 B23 = __half22float2(*(__half2*)&xB.y);
        float2 B4_ = __half22float2(*(__half2*)&xB.z);
        float2 C01 = __half22float2(*(__half2*)&xC.x);
        float2 C23 = __half22float2(*(__half2*)&xC.y);
        float2 C4_ = __half22float2(*(__half2*)&xC.z);
        float2 D01 = __half22float2(*(__half2*)&xD.x);
        float2 D23 = __half22float2(*(__half2*)&xD.y);
        float2 D4_ = __half22float2(*(__half2*)&xD.z);
        c0 += wA * A01.x + wB * B01.x + wC * C01.x + wD * D01.x;
        c1 += wA * A01.y + wB * B01.y + wC * C01.y + wD * D01.y;
        c2 += wA * A23.x + wB * B23.x + wC * C23.x + wD * D23.x;
        c3 += wA * A23.y + wB * B23.y + wC * C23.y + wD * D23.y;
        c4 += wA * A4_.x + wB * B4_.x + wC * C4_.x + wD * D4_.x;
        den += wA + wB + wC + wD;
    }

    // reduce across the 2 edge slots — afterwards all 16 lanes hold sums
#define REDH(x) x += __shfl_xor(x, 8, 64);
    REDH(c0) REDH(c1) REDH(c2) REDH(c3) REDH(c4) REDH(den)
#undef REDH

    // ---- fused epilogue (old k_rec), h = lane16 & 7, unmasked ----
    float inv = 1.f / den;                     // den>0 (self-loop guarantees)
    float xs[5] = { c0 * inv, c1 * inv, c2 * inv, c3 * inv, c4 * inv };

    float4 hA = ((const float4*)b1)[2 * h];
    float4 hB = ((const float4*)b1)[2 * h + 1];
#pragma unroll
    for (int c = 0; c < 5; ++c) {
        float xc = xs[c];
        float4 wA = *(const float4*)(W1 + c * 64 + 8 * h);
        float4 wB = *(const float4*)(W1 + c * 64 + 8 * h + 4);
        hA.x += xc * wA.x; hA.y += xc * wA.y; hA.z += xc * wA.z; hA.w += xc * wA.w;
        hB.x += xc * wB.x; hB.y += xc * wB.y; hB.z += xc * wB.z; hB.w += xc * wB.w;
    }
    float v0 = hA.x, v1 = hA.y, v2 = hA.z, v3 = hA.w;
    float v4 = hB.x, v5 = hB.y, v6 = hB.z, v7 = hB.w;
    v0 = (v0 > 0.f) ? v0 : (__expf(v0) - 1.f); // ELU
    v1 = (v1 > 0.f) ? v1 : (__expf(v1) - 1.f);
    v2 = (v2 > 0.f) ? v2 : (__expf(v2) - 1.f);
    v3 = (v3 > 0.f) ? v3 : (__expf(v3) - 1.f);
    v4 = (v4 > 0.f) ? v4 : (__expf(v4) - 1.f);
    v5 = (v5 > 0.f) ? v5 : (__expf(v5) - 1.f);
    v6 = (v6 > 0.f) ? v6 : (__expf(v6) - 1.f);
    v7 = (v7 > 0.f) ? v7 : (__expf(v7) - 1.f);

    const float4* w4 = (const float4*)(W2 + h * 16);
    float4 wq0 = w4[0], wq1 = w4[1], wq2 = w4[2], wq3 = w4[3];
    float h20 = v0 * wq0.x + v1 * wq0.z + v2 * wq1.x + v3 * wq1.z
              + v4 * wq2.x + v5 * wq2.z + v6 * wq3.x + v7 * wq3.z;
    float h21 = v0 * wq0.y + v1 * wq0.w + v2 * wq1.y + v3 * wq1.w
              + v4 * wq2.y + v5 * wq2.w + v6 * wq3.y + v7 * wq3.w;
    // reduce across the 8 heads (lane bits 0..2 — within each 16-group)
    h20 += __shfl_xor(h20, 1, 64); h20 += __shfl_xor(h20, 2, 64); h20 += __shfl_xor(h20, 4, 64);
    h21 += __shfl_xor(h21, 1, 64); h21 += __shfl_xor(h21, 2, 64); h21 += __shfl_xor(h21, 4, 64);

    if (lane16 == 0) {
        float as2v = (h20 * a_src2[0] + h21 * a_src2[1]) * LOG2E;
        float ad2v = (h20 * a_dst2[0] + h21 * a_dst2[1]) * LOG2E;
        rec[d] = make_float4(h20, h21, as2v, ad2v);
    }
}

// ---------------- layer 2: per-dst gather + log_softmax -----------------
// 8 lanes per dst (8 dsts/wave). rec.z/.w pre-scaled by log2e.
// x2-unrolled: 2 predicated 8-edge groups = 16 edges in flight.
__global__ void __launch_bounds__(256) k_gather2(
        const int* __restrict__ rbeg, const int* __restrict__ rend,
        const int* __restrict__ ssrc, const float4* __restrict__ rec,
        const float* __restrict__ b2, float* __restrict__ out) {
    int gtid = blockIdx.x * blockDim.x + threadIdx.x;
    int d    = gtid >> 3;
    int lane = threadIdx.x & 7;
    if (d >= N_NODES) return;

    int beg = rbeg[d], end = rend[d];
    float adv = rec[d].w;
    float n0 = 0.f, n1 = 0.f, den = 0.f;
    for (int k = beg; k < end; k += 16) {
        int kA = k + lane, kB = k + 8 + lane;
        bool vA = kA < end, vB = kB < end;
        int sA = ssrc[vA ? kA : beg];
        int sB = ssrc[vB ? kB : beg];
        float4 rA = rec[sA];
        float4 rB = rec[sB];
        float tA = rA.z + adv; tA = fmaxf(tA, NEG_SLOPE * tA);
        float tB = rB.z + adv; tB = fmaxf(tB, NEG_SLOPE * tB);
        float wA = vA ? __builtin_amdgcn_exp2f(tA) : 0.f;
        float wB = vB ? __builtin_amdgcn_exp2f(tB) : 0.f;
        n0 += wA * rA.x + wB * rB.x;
        n1 += wA * rA.y + wB * rB.y;
        den += wA + wB;
    }
#pragma unroll
    for (int off = 1; off < 8; off <<= 1) {
        n0  += __shfl_xor(n0,  off, 8);
        n1  += __shfl_xor(n1,  off, 8);
        den += __shfl_xor(den, off, 8);
    }
    if (lane == 0) {
        float o0 = n0 / den + b2[0];
        float o1 = n1 / den + b2[1];
        float m  = fmaxf(o0, o1);
        float lse = m + __logf(__expf(o0 - m) + __expf(o1 - m));
        *(float2*)(out + (size_t)d * 2) = make_float2(o0 - lse, o1 - lse);
    }
}

extern "C" void kernel_launch(void* const* d_in, const int* in_sizes, int n_in,
                              void* d_out, int out_size, void* d_ws, size_t ws_size,
                              hipStream_t stream) {
    const float* x      = (const float*)d_in[0];
    const int*   ei     = (const int*)d_in[1];     // [2, E] int32
    const float* W1     = (const float*)d_in[2];
    const float* a_src1 = (const float*)d_in[3];
    const float* a_dst1 = (const float*)d_in[4];
    const float* b1     = (const float*)d_in[5];
    const float* W2     = (const float*)d_in[6];
    const float* a_src2 = (const float*)d_in[7];
    const float* a_dst2 = (const float*)d_in[8];
    const float* b2     = (const float*)d_in[9];
    float* out = (float*)d_out;

    const int* src = ei;
    const int* dst = ei + N_EDGES;

    // ---- workspace layout (~28 MB). ofs+pairs live only through k_csr.
    // Everything written before read.
    int* rbeg   = (int*)d_ws;                                   // N
    int* rend   = rbeg + N_NODES;                               // N
    int* ssrc   = rend + N_NODES;                               // NCB*WINB (8 MB)
    uintptr_t pp = ((uintptr_t)(ssrc + (size_t)NCB * WINB) + 255) & ~(uintptr_t)255;
    float4*   rec  = (float4*)pp;                               // N float4 (1.6 MB)
    float*    ad1  = (float*)(rec + N_NODES);                   // N*8 fp32 (3.2 MB)
    __half*   nd   = (__half*)(ad1 + (size_t)N_NODES * 8);      // N*16 fp16 (3.2 MB, packed as+x)
    uintptr_t rg = ((uintptr_t)(nd + (size_t)N_NODES * 16) + 255) & ~(uintptr_t)255;
    int*      ofs   = (int*)rg;                                 // NPB*(NCB+1) (2.45 MB)
    unsigned* pairs = (unsigned*)(ofs + (size_t)NPB * (NCB + 1)); // E (6.4 MB)

    k_np<<<NPB + NB_NODE1, 512, 0, stream>>>(src, dst, ofs, pairs,
                                             x, W1, a_src1, a_dst1,
                                             nd, ad1);
    k_csr<<<NCB, 512, 0, stream>>>(ofs, pairs, rbeg, rend, ssrc);
    k_gather1<<<(N_NODES * 16 + 255) / 256, 256, 0, stream>>>(rbeg, rend, ssrc,
                                                              nd, ad1, b1, W1, W2,
                                                              a_src2, a_dst2, rec);
    k_gather2<<<(N_NODES * 8 + 255) / 256, 256, 0, stream>>>(rbeg, rend, ssrc,
                                                             rec, b2, out);
}